// Round 1
// baseline (591.162 us; speedup 1.0000x reference)
//
#include <hip/hip_runtime.h>
#include <cfloat>
#include <cstdint>

// VQ-VAE vector quantizer forward. Round 7: fp16 hi/lo split (was bf16),
// argmin + proj_out drop to 2 MFMA passes (was 3); W_in/W_out/codebook
// pre-scaled x16 before splitting so fp16 lo residues stay normal-range
// (denorm-flush safe); GAP_EPS widened 1e-3 -> 5e-3 to cover the 2-pass
// error tail; rescue parallelism x4 (RBLOCKS 2048 -> 8192).
#define B_      16
#define DIN     512
#define HW      1024
#define CDIM    256
#define KCODES  8192
#define NTOK    (B_ * HW)            // 16384
#define OUT_ELEMS (B_ * DIN * HW)    // 8388608
#define GAP_EPS 5e-3f
#define NSTRIP  8
#define NPART   (NSTRIP * 2)
#define CPS     (KCODES / NSTRIP)    // 1024
#define MAXR    4096
#define RCHUNK  32
#define RBLOCKS 8192
#define LOSS_SCALE (1.0f / ((float)NTOK * (float)CDIM))
// tensor pre-scale for fp16 splits of small-magnitude tensors
#define WSCALE      16.0f
#define INV_WS      0.0625f          // 1/16  (proj_in:  x * (16 W))
#define INV_WS2     0.00390625f      // 1/256 (proj_out: (16 Wo)*(16 e))
#define NEG2_INV_WS (-0.125f)        // -2/16 (argmin:   z * (16 e))

typedef __attribute__((ext_vector_type(8))) _Float16 f16x8;
typedef __attribute__((ext_vector_type(4))) float f32x4;

static __device__ __forceinline__ short f2h(float f) {
  _Float16 h = (_Float16)f;                  // RNE
  return __builtin_bit_cast(short, h);
}
static __device__ __forceinline__ float h2f(short h) {
  return (float)__builtin_bit_cast(_Float16, h);
}

#define GLL16(gsrc, ldst)                                                      \
  __builtin_amdgcn_global_load_lds(                                           \
      (const __attribute__((address_space(1))) unsigned int*)(gsrc),          \
      (__attribute__((address_space(3))) unsigned int*)(ldst), 16, 0, 0)

// ---------------- K0: fused prep: cb hi/lo + ee | W hi/lo | xT hi/lo ---------
// grid regions: [0,2048) cb, [2048,2176) weights, [2176,4224) x-transpose.
// cb/W splits store 16x the value (fp16 denorm-safe); ee stays unscaled fp32.
#define PREP_CB_BLKS 2048
#define PREP_W_BLKS  128
#define PREP_X_BLKS  2048
__global__ __launch_bounds__(256) void k_prep(
    const float* __restrict__ cb, const float* __restrict__ Win,
    const float* __restrict__ Wout, const float* __restrict__ x,
    short* __restrict__ cb_hi, short* __restrict__ cb_lo, float* __restrict__ ee,
    short* __restrict__ wi_hi, short* __restrict__ wi_lo,
    short* __restrict__ wo_hi, short* __restrict__ wo_lo,
    short* __restrict__ xT_hi, short* __restrict__ xT_lo,
    float* __restrict__ loss, int* __restrict__ rcount) {
  __shared__ float T[64][65];
  const int blk = blockIdx.x;
  const int tid = threadIdx.x;
  if (blk == 0 && tid < 2) {
    if (tid == 0) *loss = 0.0f; else *rcount = 0;
  }
  if (blk < PREP_CB_BLKS) {
    const int wid = (blk * 256 + tid) >> 6;
    const int lane = tid & 63;
    const float4 v = *(const float4*)(cb + (size_t)wid * CDIM + lane * 4);
    float s = v.x * v.x + v.y * v.y + v.z * v.z + v.w * v.w;
    const float sx = v.x * WSCALE, sy = v.y * WSCALE,
                sz = v.z * WSCALE, sw = v.w * WSCALE;
    short4 h, l;
    h.x = f2h(sx); l.x = f2h(sx - h2f(h.x));
    h.y = f2h(sy); l.y = f2h(sy - h2f(h.y));
    h.z = f2h(sz); l.z = f2h(sz - h2f(h.z));
    h.w = f2h(sw); l.w = f2h(sw - h2f(h.w));
    *(short4*)(cb_hi + (size_t)wid * CDIM + lane * 4) = h;
    *(short4*)(cb_lo + (size_t)wid * CDIM + lane * 4) = l;
#pragma unroll
    for (int off = 32; off > 0; off >>= 1) s += __shfl_down(s, off, 64);
    if (lane == 0) ee[wid] = s;
  } else if (blk < PREP_CB_BLKS + PREP_W_BLKS) {
    const int i = ((blk - PREP_CB_BLKS) * 256 + tid) * 4;
    {
      const float4 v = *(const float4*)(Win + i);
      const float sx = v.x * WSCALE, sy = v.y * WSCALE,
                  sz = v.z * WSCALE, sw = v.w * WSCALE;
      short4 h, l;
      h.x = f2h(sx); l.x = f2h(sx - h2f(h.x));
      h.y = f2h(sy); l.y = f2h(sy - h2f(h.y));
      h.z = f2h(sz); l.z = f2h(sz - h2f(h.z));
      h.w = f2h(sw); l.w = f2h(sw - h2f(h.w));
      *(short4*)(wi_hi + i) = h; *(short4*)(wi_lo + i) = l;
    }
    {
      const float4 v = *(const float4*)(Wout + i);
      const float sx = v.x * WSCALE, sy = v.y * WSCALE,
                  sz = v.z * WSCALE, sw = v.w * WSCALE;
      short4 h, l;
      h.x = f2h(sx); l.x = f2h(sx - h2f(h.x));
      h.y = f2h(sy); l.y = f2h(sy - h2f(h.y));
      h.z = f2h(sz); l.z = f2h(sz - h2f(h.z));
      h.w = f2h(sw); l.w = f2h(sw - h2f(h.w));
      *(short4*)(wo_hi + i) = h; *(short4*)(wo_lo + i) = l;
    }
  } else {
    const int id = blk - PREP_CB_BLKS - PREP_W_BLKS;
    const int xb = id & 255, yb = id >> 8;
    const int b = xb >> 4;
    const int hw0 = (xb & 15) * 64;
    const int din0 = yb * 64;
    {
      const int r = tid >> 2;
      const int c = tid & 3;
      const float* src = x + ((size_t)b * DIN + din0 + r) * HW + hw0 + c * 16;
#pragma unroll
      for (int j = 0; j < 4; ++j) {
        const float4 v = *(const float4*)(src + j * 4);
        T[r][c * 16 + j * 4 + 0] = v.x;
        T[r][c * 16 + j * 4 + 1] = v.y;
        T[r][c * 16 + j * 4 + 2] = v.z;
        T[r][c * 16 + j * 4 + 3] = v.w;
      }
    }
    __syncthreads();
    {
      const int tt = tid & 63;
      const int c2 = tid >> 6;
      short h[16], l[16];
#pragma unroll
      for (int j = 0; j < 16; ++j) {
        const float f = T[c2 * 16 + j][tt];
        h[j] = f2h(f); l[j] = f2h(f - h2f(h[j]));
      }
      const size_t base = ((size_t)b * HW + hw0 + tt) * DIN + din0 + c2 * 16;
      *(f16x8*)(xT_hi + base)     = *(f16x8*)&h[0];
      *(f16x8*)(xT_hi + base + 8) = *(f16x8*)&h[8];
      *(f16x8*)(xT_lo + base)     = *(f16x8*)&l[0];
      *(f16x8*)(xT_lo + base + 8) = *(f16x8*)&l[8];
    }
  }
}

// ---------------- K1: proj_in MFMA: z = xT @ (16 Win)^T / 16 + b_in ----------
// 3 fp16 passes: hh + h*lo(B) + lo(A)*h — dropped lo*lo term ~2^-22.
__global__ __launch_bounds__(256, 2) void k_proj_in_mfma(
    const short* __restrict__ xT_hi, const short* __restrict__ xT_lo,
    const short* __restrict__ wi_hi, const short* __restrict__ wi_lo,
    const float* __restrict__ bin,
    short* __restrict__ z_hi, short* __restrict__ z_lo) {
  __shared__ short lds_s[4 * 128 * 32];
  char* ldsc = (char*)lds_s;
  const int tid = threadIdx.x;
  const int w = tid >> 6, lane = tid & 63;
  const int quad = lane >> 4, l16 = lane & 15;
  const int wm = w >> 1, wn = w & 1;
  const int tok0 = blockIdx.x * 128;
  const int cd0 = blockIdx.y * 128;

  const int uA = (w << 6) + lane, uB = uA + 256;
  const int tA = uA >> 2, pA = uA & 3, qA = pA ^ ((tA >> 1) & 3);
  const int tB = uB >> 2, pB = uB & 3, qB = pB ^ ((tB >> 1) & 3);
  const int offA = tA * DIN + qA * 8;
  const int offB = tB * DIN + qB * 8;
  const short* gAh0 = xT_hi + (size_t)tok0 * DIN + offA;
  const short* gAh1 = xT_hi + (size_t)tok0 * DIN + offB;
  const short* gAl0 = xT_lo + (size_t)tok0 * DIN + offA;
  const short* gAl1 = xT_lo + (size_t)tok0 * DIN + offB;
  const short* gBh0 = wi_hi + (size_t)cd0 * DIN + offA;
  const short* gBh1 = wi_hi + (size_t)cd0 * DIN + offB;
  const short* gBl0 = wi_lo + (size_t)cd0 * DIN + offA;
  const short* gBl1 = wi_lo + (size_t)cd0 * DIN + offB;

  int aoffs[4], boffs[4];
#pragma unroll
  for (int mi = 0; mi < 4; ++mi) {
    const int t = wm * 64 + mi * 16 + l16;
    aoffs[mi] = t * 64 + (quad ^ ((t >> 1) & 3)) * 16;
  }
#pragma unroll
  for (int ni = 0; ni < 4; ++ni) {
    const int t = wn * 64 + ni * 16 + l16;
    boffs[ni] = 16384 + t * 64 + (quad ^ ((t >> 1) & 3)) * 16;
  }

  f32x4 acc[4][4];
#pragma unroll
  for (int mi = 0; mi < 4; ++mi)
#pragma unroll
    for (int ni = 0; ni < 4; ++ni) acc[mi][ni] = (f32x4){0.f, 0.f, 0.f, 0.f};

  for (int kb = 0; kb < DIN; kb += 32) {
    __syncthreads();
    GLL16(gAh0 + kb, ldsc + ((0 * 4 + w) << 10));
    GLL16(gAh1 + kb, ldsc + ((1 * 4 + w) << 10));
    GLL16(gAl0 + kb, ldsc + ((2 * 4 + w) << 10));
    GLL16(gAl1 + kb, ldsc + ((3 * 4 + w) << 10));
    GLL16(gBh0 + kb, ldsc + ((4 * 4 + w) << 10));
    GLL16(gBh1 + kb, ldsc + ((5 * 4 + w) << 10));
    GLL16(gBl0 + kb, ldsc + ((6 * 4 + w) << 10));
    GLL16(gBl1 + kb, ldsc + ((7 * 4 + w) << 10));
    __syncthreads();
    f16x8 ah[4], al[4], bh[4], bl[4];
#pragma unroll
    for (int mi = 0; mi < 4; ++mi) {
      ah[mi] = *(const f16x8*)(ldsc + aoffs[mi]);
      al[mi] = *(const f16x8*)(ldsc + 8192 + aoffs[mi]);
    }
#pragma unroll
    for (int ni = 0; ni < 4; ++ni) {
      bh[ni] = *(const f16x8*)(ldsc + boffs[ni]);
      bl[ni] = *(const f16x8*)(ldsc + 8192 + boffs[ni]);
    }
#pragma unroll
    for (int mi = 0; mi < 4; ++mi)
#pragma unroll
      for (int ni = 0; ni < 4; ++ni) {
        f32x4 c = acc[mi][ni];
        c = __builtin_amdgcn_mfma_f32_16x16x32_f16(ah[mi], bh[ni], c, 0, 0, 0);
        c = __builtin_amdgcn_mfma_f32_16x16x32_f16(ah[mi], bl[ni], c, 0, 0, 0);
        c = __builtin_amdgcn_mfma_f32_16x16x32_f16(al[mi], bh[ni], c, 0, 0, 0);
        acc[mi][ni] = c;
      }
  }
  float bv[4];
#pragma unroll
  for (int ni = 0; ni < 4; ++ni) bv[ni] = bin[cd0 + wn * 64 + ni * 16 + l16];
#pragma unroll
  for (int mi = 0; mi < 4; ++mi)
#pragma unroll
    for (int r = 0; r < 4; ++r) {
      const int t = tok0 + wm * 64 + mi * 16 + quad * 4 + r;
#pragma unroll
      for (int ni = 0; ni < 4; ++ni) {
        const int cd = cd0 + wn * 64 + ni * 16 + l16;
        const float o = acc[mi][ni][r] * INV_WS + bv[ni];
        const short h = f2h(o);
        z_hi[(size_t)t * CDIM + cd] = h;
        z_lo[(size_t)t * CDIM + cd] = f2h(o - h2f(h));
      }
    }
}

// ---------------- K2: MFMA distance GEMM + argmin -----------------------------
// 2 fp16 passes: z_hi * (e_hi + e_lo). Dropped z_lo*e pass -> distance error
// std ~4.5e-4 (max ~2.7e-3 over 16k tokens), covered by GAP_EPS=5e-3 rescue.
// A_lo never staged: 6 GLL16 / K-step, 24 KB LDS.
__global__ __launch_bounds__(256, 2) void k_argmin_mfma(
    const short* __restrict__ z_hi,
    const short* __restrict__ cb_hi, const short* __restrict__ cb_lo,
    const float* __restrict__ ee,
    float* __restrict__ pmv, int* __restrict__ pmi, float* __restrict__ psv) {
  __shared__ short lds_s[3 * 128 * 32];
  char* ldsc = (char*)lds_s;
  const int tid = threadIdx.x;
  const int w = tid >> 6, lane = tid & 63;
  const int quad = lane >> 4, l16 = lane & 15;
  const int wm = w >> 1, wn = w & 1;
  const int tok0 = blockIdx.x * 128;
  const int cbase = blockIdx.y * CPS;

  const int uA = (w << 6) + lane, uB = uA + 256;
  const int tA = uA >> 2, pA = uA & 3, qA = pA ^ ((tA >> 1) & 3);
  const int tB = uB >> 2, pB = uB & 3, qB = pB ^ ((tB >> 1) & 3);
  const int offA = tA * CDIM + qA * 8;
  const int offB = tB * CDIM + qB * 8;
  const short* gAh0 = z_hi + (size_t)tok0 * CDIM + offA;
  const short* gAh1 = z_hi + (size_t)tok0 * CDIM + offB;

  int aoffs[4], boffs[4];
#pragma unroll
  for (int mi = 0; mi < 4; ++mi) {
    const int t = wm * 64 + mi * 16 + l16;
    aoffs[mi] = t * 64 + (quad ^ ((t >> 1) & 3)) * 16;
  }
#pragma unroll
  for (int ni = 0; ni < 4; ++ni) {
    const int t = wn * 64 + ni * 16 + l16;
    boffs[ni] = 8192 + t * 64 + (quad ^ ((t >> 1) & 3)) * 16;
  }

  float mv[16], sv[16]; int bidx[16];
#pragma unroll
  for (int j = 0; j < 16; ++j) { mv[j] = FLT_MAX; sv[j] = FLT_MAX; bidx[j] = 0; }

  for (int ct = 0; ct < CPS / 128; ++ct) {
    const int ctile = cbase + ct * 128;
    const short* gBh0 = cb_hi + (size_t)ctile * CDIM + offA;
    const short* gBh1 = cb_hi + (size_t)ctile * CDIM + offB;
    const short* gBl0 = cb_lo + (size_t)ctile * CDIM + offA;
    const short* gBl1 = cb_lo + (size_t)ctile * CDIM + offB;
    f32x4 acc[4][4];
#pragma unroll
    for (int mi = 0; mi < 4; ++mi)
#pragma unroll
      for (int ni = 0; ni < 4; ++ni) acc[mi][ni] = (f32x4){0.f, 0.f, 0.f, 0.f};

    for (int kb = 0; kb < CDIM; kb += 32) {
      __syncthreads();
      GLL16(gAh0 + kb, ldsc + ((0 * 4 + w) << 10));
      GLL16(gAh1 + kb, ldsc + ((1 * 4 + w) << 10));
      GLL16(gBh0 + kb, ldsc + ((2 * 4 + w) << 10));
      GLL16(gBh1 + kb, ldsc + ((3 * 4 + w) << 10));
      GLL16(gBl0 + kb, ldsc + ((4 * 4 + w) << 10));
      GLL16(gBl1 + kb, ldsc + ((5 * 4 + w) << 10));
      __syncthreads();
      f16x8 ah[4], bh[4], bl[4];
#pragma unroll
      for (int mi = 0; mi < 4; ++mi)
        ah[mi] = *(const f16x8*)(ldsc + aoffs[mi]);
#pragma unroll
      for (int ni = 0; ni < 4; ++ni) {
        bh[ni] = *(const f16x8*)(ldsc + boffs[ni]);
        bl[ni] = *(const f16x8*)(ldsc + 8192 + boffs[ni]);
      }
#pragma unroll
      for (int mi = 0; mi < 4; ++mi)
#pragma unroll
        for (int ni = 0; ni < 4; ++ni) {
          f32x4 c = acc[mi][ni];
          c = __builtin_amdgcn_mfma_f32_16x16x32_f16(ah[mi], bh[ni], c, 0, 0, 0);
          c = __builtin_amdgcn_mfma_f32_16x16x32_f16(ah[mi], bl[ni], c, 0, 0, 0);
          acc[mi][ni] = c;
        }
    }
    float eev[4];
#pragma unroll
    for (int ni = 0; ni < 4; ++ni) eev[ni] = ee[ctile + wn * 64 + ni * 16 + l16];
    const int cb2 = ctile + wn * 64 + l16;
#pragma unroll
    for (int mi = 0; mi < 4; ++mi)
#pragma unroll
      for (int r = 0; r < 4; ++r) {
        const int j = mi * 4 + r;
#pragma unroll
        for (int ni = 0; ni < 4; ++ni) {
          const float s = fmaf(NEG2_INV_WS, acc[mi][ni][r], eev[ni]);
          // 5-op update: 2nd-best via min/max, best via predicated move
          sv[j] = fminf(sv[j], fmaxf(mv[j], s));
          if (s < mv[j]) { mv[j] = s; bidx[j] = cb2 + ni * 16; }
        }
      }
  }
#pragma unroll
  for (int off = 1; off < 16; off <<= 1) {
#pragma unroll
    for (int j = 0; j < 16; ++j) {
      const float ov = __shfl_xor(mv[j], off, 64);
      const int   oi = __shfl_xor(bidx[j], off, 64);
      const float os = __shfl_xor(sv[j], off, 64);
      const float snew = fminf(fminf(sv[j], os), fmaxf(mv[j], ov));
      if (ov < mv[j] || (ov == mv[j] && oi < bidx[j])) { mv[j] = ov; bidx[j] = oi; }
      sv[j] = snew;
    }
  }
  if (l16 == 0) {
    const int strip = blockIdx.y * 2 + wn;
#pragma unroll
    for (int j = 0; j < 16; ++j) {
      const int mi = j >> 2, r = j & 3;
      const int t = tok0 + wm * 64 + mi * 16 + quad * 4 + r;
      const size_t o = (size_t)strip * NTOK + t;
      pmv[o] = mv[j]; pmi[o] = bidx[j]; psv[o] = sv[j];
    }
  }
}

// ---------------- K2b: merge 16 partials + provisional loss (fused) -----------
__global__ __launch_bounds__(256) void k_merge_loss(
    const float* __restrict__ pmv, const int* __restrict__ pmi,
    const float* __restrict__ psv,
    const short* __restrict__ z_hi, const short* __restrict__ z_lo,
    const float* __restrict__ cb,
    int* __restrict__ idxi, float* __restrict__ idx_f,
    int* __restrict__ rlist, int* __restrict__ rcount,
    float* __restrict__ loss) {
  __shared__ float lpart[4];
  const int tid = threadIdx.x;
  const int wv = tid >> 6, lane = tid & 63;
  const int t = blockIdx.x * 4 + wv;
  float mv = FLT_MAX, sv = FLT_MAX; int mi = 0x7fffffff;
  if (lane < NPART) {
    mv = pmv[(size_t)lane * NTOK + t];
    mi = pmi[(size_t)lane * NTOK + t];
    sv = psv[(size_t)lane * NTOK + t];
  }
#pragma unroll
  for (int off = 1; off < 16; off <<= 1) {
    const float ov = __shfl_xor(mv, off, 64);
    const int   oi = __shfl_xor(mi, off, 64);
    const float os = __shfl_xor(sv, off, 64);
    const float snew = fminf(fminf(sv, os), fmaxf(mv, ov));
    if (ov < mv || (ov == mv && oi < mi)) { mv = ov; mi = oi; }
    sv = snew;
  }
  const int mif = __shfl(mi, 0, 64);
  // loss partial: 4 dims per lane
  const short4 h4 = *(const short4*)(z_hi + (size_t)t * CDIM + lane * 4);
  const short4 l4 = *(const short4*)(z_lo + (size_t)t * CDIM + lane * 4);
  const float4 qv = *(const float4*)(cb + (size_t)mif * CDIM + lane * 4);
  const float dx = qv.x - (h2f(h4.x) + h2f(l4.x));
  const float dy = qv.y - (h2f(h4.y) + h2f(l4.y));
  const float dz = qv.z - (h2f(h4.z) + h2f(l4.z));
  const float dw = qv.w - (h2f(h4.w) + h2f(l4.w));
  float s = dx * dx + dy * dy + dz * dz + dw * dw;
#pragma unroll
  for (int off = 32; off > 0; off >>= 1) s += __shfl_down(s, off, 64);
  if (lane == 0) {
    idxi[t] = mif;
    idx_f[t] = (float)mif;
    lpart[wv] = s;
    if (sv - mv < GAP_EPS) {
      const int pos = atomicAdd(rcount, 1);
      if (pos < MAXR) rlist[pos] = t;
    }
  }
  __syncthreads();
  if (tid == 0) {
    atomicAdd(loss, (lpart[0] + lpart[1] + lpart[2] + lpart[3]) * LOSS_SCALE);
  }
}

// ---------------- K2c: chunked fp64 rescore -----------------------------------
__global__ __launch_bounds__(256) void k_rescue_chunk(
    const short* __restrict__ z_hi, const short* __restrict__ z_lo,
    const float* __restrict__ cb,
    const int* __restrict__ rlist, const int* __restrict__ rcount,
    double* __restrict__ slotv, int* __restrict__ sloti) {
  const int cnt0 = *rcount;
  const int cnt = cnt0 < MAXR ? cnt0 : MAXR;
  const int li0 = blockIdx.x >> 5;
  const int chunk = blockIdx.x & (RCHUNK - 1);
  if (li0 >= cnt) return;
  __shared__ float zrow[CDIM];
  __shared__ double rv[256];
  __shared__ int ri[256];
  const int tid = threadIdx.x;
  for (int li = li0; li < cnt; li += RBLOCKS / RCHUNK) {
    const int t = rlist[li];
    zrow[tid] = h2f(z_hi[(size_t)t * CDIM + tid]) + h2f(z_lo[(size_t)t * CDIM + tid]);
    __syncthreads();
    const int k = chunk * 256 + tid;
    const float* e = cb + (size_t)k * CDIM;
    double s0 = 0.0, s1 = 0.0, s2 = 0.0, s3 = 0.0;
    for (int c = 0; c < CDIM; c += 4) {
      const float4 ev = *(const float4*)(e + c);
      const double d0 = (double)zrow[c]     - (double)ev.x;
      const double d1 = (double)zrow[c + 1] - (double)ev.y;
      const double d2 = (double)zrow[c + 2] - (double)ev.z;
      const double d3 = (double)zrow[c + 3] - (double)ev.w;
      s0 += d0 * d0; s1 += d1 * d1; s2 += d2 * d2; s3 += d3 * d3;
    }
    rv[tid] = (s0 + s1) + (s2 + s3);
    ri[tid] = k;
    __syncthreads();
    for (int off = 128; off > 0; off >>= 1) {
      if (tid < off) {
        if (rv[tid + off] < rv[tid] ||
            (rv[tid + off] == rv[tid] && ri[tid + off] < ri[tid])) {
          rv[tid] = rv[tid + off]; ri[tid] = ri[tid + off];
        }
      }
      __syncthreads();
    }
    if (tid == 0) {
      slotv[(size_t)li * RCHUNK + chunk] = rv[0];
      sloti[(size_t)li * RCHUNK + chunk] = ri[0];
    }
    __syncthreads();
  }
}

// ---------------- K2d: fold chunk slots, patch indices + loss delta -----------
__global__ __launch_bounds__(256) void k_rescue_fin(
    const double* __restrict__ slotv, const int* __restrict__ sloti,
    const int* __restrict__ rlist, const int* __restrict__ rcount,
    const short* __restrict__ z_hi, const short* __restrict__ z_lo,
    const float* __restrict__ cb,
    int* __restrict__ idxi, float* __restrict__ idx_f, float* __restrict__ loss) {
  const int cnt0 = *rcount;
  const int cnt = cnt0 < MAXR ? cnt0 : MAXR;
  const int tid = threadIdx.x;
  const int wv = tid >> 6, lane = tid & 63;
  for (int li = wv; li < cnt; li += 4) {
    double bv = 1e300; int bx = 0x7fffffff;
    if (lane < RCHUNK) {
      bv = slotv[(size_t)li * RCHUNK + lane];
      bx = sloti[(size_t)li * RCHUNK + lane];
    }
#pragma unroll
    for (int off = 1; off < 32; off <<= 1) {
      const double ov = __shfl_xor(bv, off, 64);
      const int   oi = __shfl_xor(bx, off, 64);
      if (ov < bv || (ov == bv && oi < bx)) { bv = ov; bx = oi; }
    }
    const int newi = __shfl(bx, 0, 64);
    const int t = rlist[li];
    const int oldi = idxi[t];
    if (newi != oldi) {
      // loss delta over 4 dims/lane
      const short4 h4 = *(const short4*)(z_hi + (size_t)t * CDIM + lane * 4);
      const short4 l4 = *(const short4*)(z_lo + (size_t)t * CDIM + lane * 4);
      const float4 qn = *(const float4*)(cb + (size_t)newi * CDIM + lane * 4);
      const float4 qo = *(const float4*)(cb + (size_t)oldi * CDIM + lane * 4);
      const float zx = h2f(h4.x) + h2f(l4.x);
      const float zy = h2f(h4.y) + h2f(l4.y);
      const float zz = h2f(h4.z) + h2f(l4.z);
      const float zw = h2f(h4.w) + h2f(l4.w);
      float d = (qn.x - zx) * (qn.x - zx) - (qo.x - zx) * (qo.x - zx)
              + (qn.y - zy) * (qn.y - zy) - (qo.y - zy) * (qo.y - zy)
              + (qn.z - zz) * (qn.z - zz) - (qo.z - zz) * (qo.z - zz)
              + (qn.w - zw) * (qn.w - zw) - (qo.w - zw) * (qo.w - zw);
#pragma unroll
      for (int off = 32; off > 0; off >>= 1) d += __shfl_down(d, off, 64);
      if (lane == 0) {
        idxi[t] = newi;
        idx_f[t] = (float)newi;
        atomicAdd(loss, d * LOSS_SCALE);
      }
    }
  }
}

// ---------------- K3: proj_out MFMA (transposed): out[din][tok] ---------------
// 2 fp16 passes: wo_hi * (cb_hi + cb_lo); both scaled x16 -> epilogue /256.
__global__ __launch_bounds__(256, 2) void k_proj_out_mfma(
    const short* __restrict__ wo_hi,
    const short* __restrict__ cb_hi, const short* __restrict__ cb_lo,
    const int* __restrict__ idxi, const float* __restrict__ bout,
    float* __restrict__ out) {
  __shared__ short lds_s[3 * 128 * 32];
  char* ldsc = (char*)lds_s;
  const int tid = threadIdx.x;
  const int w = tid >> 6, lane = tid & 63;
  const int quad = lane >> 4, l16 = lane & 15;
  const int wm = w >> 1, wn = w & 1;
  const int tok0 = blockIdx.x * 128;
  const int din0 = blockIdx.y * 128;

  const int uA = (w << 6) + lane, uB = uA + 256;
  const int tA = uA >> 2, pA = uA & 3, qA = pA ^ ((tA >> 1) & 3);
  const int tB = uB >> 2, pB = uB & 3, qB = pB ^ ((tB >> 1) & 3);
  const short* gAh0 = wo_hi + (size_t)(din0 + tA) * CDIM + qA * 8;
  const short* gAh1 = wo_hi + (size_t)(din0 + tB) * CDIM + qB * 8;
  const int iA = idxi[tok0 + tA];
  const int iB = idxi[tok0 + tB];
  const short* gBh0 = cb_hi + (size_t)iA * CDIM + qA * 8;
  const short* gBh1 = cb_hi + (size_t)iB * CDIM + qB * 8;
  const short* gBl0 = cb_lo + (size_t)iA * CDIM + qA * 8;
  const short* gBl1 = cb_lo + (size_t)iB * CDIM + qB * 8;

  int aoffs[4], boffs[4];
#pragma unroll
  for (int mi = 0; mi < 4; ++mi) {
    const int t = wm * 64 + mi * 16 + l16;
    aoffs[mi] = t * 64 + (quad ^ ((t >> 1) & 3)) * 16;
  }
#pragma unroll
  for (int ni = 0; ni < 4; ++ni) {
    const int t = wn * 64 + ni * 16 + l16;
    boffs[ni] = 8192 + t * 64 + (quad ^ ((t >> 1) & 3)) * 16;
  }

  f32x4 acc[4][4];
#pragma unroll
  for (int mi = 0; mi < 4; ++mi)
#pragma unroll
    for (int ni = 0; ni < 4; ++ni) acc[mi][ni] = (f32x4){0.f, 0.f, 0.f, 0.f};

  for (int kb = 0; kb < CDIM; kb += 32) {
    __syncthreads();
    GLL16(gAh0 + kb, ldsc + ((0 * 4 + w) << 10));
    GLL16(gAh1 + kb, ldsc + ((1 * 4 + w) << 10));
    GLL16(gBh0 + kb, ldsc + ((2 * 4 + w) << 10));
    GLL16(gBh1 + kb, ldsc + ((3 * 4 + w) << 10));
    GLL16(gBl0 + kb, ldsc + ((4 * 4 + w) << 10));
    GLL16(gBl1 + kb, ldsc + ((5 * 4 + w) << 10));
    __syncthreads();
    f16x8 ah[4], bh[4], bl[4];
#pragma unroll
    for (int mi = 0; mi < 4; ++mi)
      ah[mi] = *(const f16x8*)(ldsc + aoffs[mi]);
#pragma unroll
    for (int ni = 0; ni < 4; ++ni) {
      bh[ni] = *(const f16x8*)(ldsc + boffs[ni]);
      bl[ni] = *(const f16x8*)(ldsc + 8192 + boffs[ni]);
    }
#pragma unroll
    for (int mi = 0; mi < 4; ++mi)
#pragma unroll
      for (int ni = 0; ni < 4; ++ni) {
        f32x4 c = acc[mi][ni];
        c = __builtin_amdgcn_mfma_f32_16x16x32_f16(ah[mi], bh[ni], c, 0, 0, 0);
        c = __builtin_amdgcn_mfma_f32_16x16x32_f16(ah[mi], bl[ni], c, 0, 0, 0);
        acc[mi][ni] = c;
      }
  }
  const int b = tok0 >> 10;
  const int hwb = tok0 & (HW - 1);
  float* ob = out + (size_t)b * DIN * HW;
#pragma unroll
  for (int mi = 0; mi < 4; ++mi)
#pragma unroll
    for (int r = 0; r < 4; ++r) {
      const int din = din0 + wm * 64 + mi * 16 + quad * 4 + r;
      const float bb = bout[din];
#pragma unroll
      for (int ni = 0; ni < 4; ++ni) {
        const int hw = hwb + wn * 64 + ni * 16 + l16;
        ob[(size_t)din * HW + hw] = acc[mi][ni][r] * INV_WS2 + bb;
      }
    }
}

extern "C" void kernel_launch(void* const* d_in, const int* in_sizes, int n_in,
                              void* d_out, int out_size, void* d_ws, size_t ws_size,
                              hipStream_t stream) {
  const float* x    = (const float*)d_in[0];
  const float* Win  = (const float*)d_in[1];
  const float* bin  = (const float*)d_in[2];
  const float* Wout = (const float*)d_in[3];
  const float* bout = (const float*)d_in[4];
  const float* cb   = (const float*)d_in[5];

  float* out   = (float*)d_out;
  float* idx_f = out + OUT_ELEMS;
  float* loss  = out + OUT_ELEMS + NTOK;

  char* w = (char*)d_ws;
  size_t off = 0;
  short* z_hi  = (short*)(w + off); off += (size_t)NTOK * CDIM * 2;
  short* z_lo  = (short*)(w + off); off += (size_t)NTOK * CDIM * 2;
  short* cb_hi = (short*)(w + off); off += (size_t)KCODES * CDIM * 2;
  short* cb_lo = (short*)(w + off); off += (size_t)KCODES * CDIM * 2;
  short* xT_hi = (short*)(w + off); off += (size_t)NTOK * DIN * 2;
  short* xT_lo = (short*)(w + off); off += (size_t)NTOK * DIN * 2;
  short* wi_hi = (short*)(w + off); off += (size_t)CDIM * DIN * 2;
  short* wi_lo = (short*)(w + off); off += (size_t)CDIM * DIN * 2;
  short* wo_hi = (short*)(w + off); off += (size_t)DIN * CDIM * 2;
  short* wo_lo = (short*)(w + off); off += (size_t)DIN * CDIM * 2;
  float* ee    = (float*)(w + off); off += (size_t)KCODES * 4;
  int*   idxi  = (int*)(w + off);   off += (size_t)NTOK * 4;
  float* pmv   = (float*)(w + off); off += (size_t)NPART * NTOK * 4;
  int*   pmi   = (int*)(w + off);   off += (size_t)NPART * NTOK * 4;
  float* psv   = (float*)(w + off); off += (size_t)NPART * NTOK * 4;
  int*   rlist = (int*)(w + off);   off += (size_t)MAXR * 4;
  int*   rcount= (int*)(w + off);   off += 256;
  double* slotv= (double*)(w + off);off += (size_t)MAXR * RCHUNK * 8;
  int*   sloti = (int*)(w + off);   off += (size_t)MAXR * RCHUNK * 4;

  k_prep        <<<dim3(PREP_CB_BLKS + PREP_W_BLKS + PREP_X_BLKS),
                   dim3(256), 0, stream>>>(cb, Win, Wout, x, cb_hi, cb_lo, ee,
                                           wi_hi, wi_lo, wo_hi, wo_lo,
                                           xT_hi, xT_lo, loss, rcount);
  k_proj_in_mfma<<<dim3(NTOK / 128, CDIM / 128), dim3(256), 0, stream>>>(
      xT_hi, xT_lo, wi_hi, wi_lo, bin, z_hi, z_lo);
  k_argmin_mfma <<<dim3(NTOK / 128, NSTRIP), dim3(256), 0, stream>>>(
      z_hi, cb_hi, cb_lo, ee, pmv, pmi, psv);
  k_merge_loss  <<<dim3(NTOK / 4), dim3(256), 0, stream>>>(
      pmv, pmi, psv, z_hi, z_lo, cb, idxi, idx_f, rlist, rcount, loss);
  k_rescue_chunk<<<dim3(RBLOCKS), dim3(256), 0, stream>>>(
      z_hi, z_lo, cb, rlist, rcount, slotv, sloti);
  k_rescue_fin  <<<dim3(1), dim3(256), 0, stream>>>(
      slotv, sloti, rlist, rcount, z_hi, z_lo, cb, idxi, idx_f, loss);
  k_proj_out_mfma<<<dim3(NTOK / 128, DIN / 128), dim3(256), 0, stream>>>(
      wo_hi, cb_hi, cb_lo, idxi, bout, out);
}

// Round 2
// 477.221 us; speedup vs baseline: 1.2388x; 1.2388x over previous
//
#include <hip/hip_runtime.h>
#include <cfloat>
#include <cstdint>

// VQ-VAE vector quantizer forward. Round 8: candidate-rescue architecture.
// fp16 hi/lo split; argmin 2 MFMA passes tracking per-partial top-2(+idx) and
// 3rd-best value; merge kernel fp64-rescores the 32 per-partial-top-2
// candidates for EVERY token (exact winner), and only falls back to the fp64
// full scan when merged m3 <= m1 + band (band = 4*||z_lo||*Emax + slack),
// which is provably sufficient for candidate completeness and fires ~never.
#define B_      16
#define DIN     512
#define HW      1024
#define CDIM    256
#define KCODES  8192
#define NTOK    (B_ * HW)            // 16384
#define OUT_ELEMS (B_ * DIN * HW)    // 8388608
#define NSTRIP  8
#define NPART   (NSTRIP * 2)
#define CPS     (KCODES / NSTRIP)    // 1024
#define MAXR    4096
#define RCHUNK  32
#define RBLOCKS 2048
#define LOSS_SCALE (1.0f / ((float)NTOK * (float)CDIM))
// tensor pre-scale for fp16 splits of small-magnitude tensors
#define WSCALE      16.0f
#define INV_WS      0.0625f          // 1/16  (proj_in:  x * (16 W))
#define INV_WS2     0.00390625f      // 1/256 (proj_out: (16 Wo)*(16 e))
#define NEG2_INV_WS (-0.125f)        // -2/16 (argmin:   z * (16 e))
// ||e||max upper bound: ||e||^2 = 0.0025*chi2_256, P(>2.25) ~ 0 (28 sigma).
#define EMAX_BOUND  1.5f

typedef __attribute__((ext_vector_type(8))) _Float16 f16x8;
typedef __attribute__((ext_vector_type(4))) float f32x4;

static __device__ __forceinline__ short f2h(float f) {
  _Float16 h = (_Float16)f;                  // RNE
  return __builtin_bit_cast(short, h);
}
static __device__ __forceinline__ float h2f(short h) {
  return (float)__builtin_bit_cast(_Float16, h);
}

#define GLL16(gsrc, ldst)                                                      \
  __builtin_amdgcn_global_load_lds(                                           \
      (const __attribute__((address_space(1))) unsigned int*)(gsrc),          \
      (__attribute__((address_space(3))) unsigned int*)(ldst), 16, 0, 0)

// ---------------- K0: fused prep: cb hi/lo + ee | W hi/lo | xT hi/lo ---------
#define PREP_CB_BLKS 2048
#define PREP_W_BLKS  128
#define PREP_X_BLKS  2048
__global__ __launch_bounds__(256) void k_prep(
    const float* __restrict__ cb, const float* __restrict__ Win,
    const float* __restrict__ Wout, const float* __restrict__ x,
    short* __restrict__ cb_hi, short* __restrict__ cb_lo, float* __restrict__ ee,
    short* __restrict__ wi_hi, short* __restrict__ wi_lo,
    short* __restrict__ wo_hi, short* __restrict__ wo_lo,
    short* __restrict__ xT_hi, short* __restrict__ xT_lo,
    float* __restrict__ loss, int* __restrict__ rcount) {
  __shared__ float T[64][65];
  const int blk = blockIdx.x;
  const int tid = threadIdx.x;
  if (blk == 0 && tid < 2) {
    if (tid == 0) *loss = 0.0f; else *rcount = 0;
  }
  if (blk < PREP_CB_BLKS) {
    const int wid = (blk * 256 + tid) >> 6;
    const int lane = tid & 63;
    const float4 v = *(const float4*)(cb + (size_t)wid * CDIM + lane * 4);
    float s = v.x * v.x + v.y * v.y + v.z * v.z + v.w * v.w;
    const float sx = v.x * WSCALE, sy = v.y * WSCALE,
                sz = v.z * WSCALE, sw = v.w * WSCALE;
    short4 h, l;
    h.x = f2h(sx); l.x = f2h(sx - h2f(h.x));
    h.y = f2h(sy); l.y = f2h(sy - h2f(h.y));
    h.z = f2h(sz); l.z = f2h(sz - h2f(h.z));
    h.w = f2h(sw); l.w = f2h(sw - h2f(h.w));
    *(short4*)(cb_hi + (size_t)wid * CDIM + lane * 4) = h;
    *(short4*)(cb_lo + (size_t)wid * CDIM + lane * 4) = l;
#pragma unroll
    for (int off = 32; off > 0; off >>= 1) s += __shfl_down(s, off, 64);
    if (lane == 0) ee[wid] = s;
  } else if (blk < PREP_CB_BLKS + PREP_W_BLKS) {
    const int i = ((blk - PREP_CB_BLKS) * 256 + tid) * 4;
    {
      const float4 v = *(const float4*)(Win + i);
      const float sx = v.x * WSCALE, sy = v.y * WSCALE,
                  sz = v.z * WSCALE, sw = v.w * WSCALE;
      short4 h, l;
      h.x = f2h(sx); l.x = f2h(sx - h2f(h.x));
      h.y = f2h(sy); l.y = f2h(sy - h2f(h.y));
      h.z = f2h(sz); l.z = f2h(sz - h2f(h.z));
      h.w = f2h(sw); l.w = f2h(sw - h2f(h.w));
      *(short4*)(wi_hi + i) = h; *(short4*)(wi_lo + i) = l;
    }
    {
      const float4 v = *(const float4*)(Wout + i);
      const float sx = v.x * WSCALE, sy = v.y * WSCALE,
                  sz = v.z * WSCALE, sw = v.w * WSCALE;
      short4 h, l;
      h.x = f2h(sx); l.x = f2h(sx - h2f(h.x));
      h.y = f2h(sy); l.y = f2h(sy - h2f(h.y));
      h.z = f2h(sz); l.z = f2h(sz - h2f(h.z));
      h.w = f2h(sw); l.w = f2h(sw - h2f(h.w));
      *(short4*)(wo_hi + i) = h; *(short4*)(wo_lo + i) = l;
    }
  } else {
    const int id = blk - PREP_CB_BLKS - PREP_W_BLKS;
    const int xb = id & 255, yb = id >> 8;
    const int b = xb >> 4;
    const int hw0 = (xb & 15) * 64;
    const int din0 = yb * 64;
    {
      const int r = tid >> 2;
      const int c = tid & 3;
      const float* src = x + ((size_t)b * DIN + din0 + r) * HW + hw0 + c * 16;
#pragma unroll
      for (int j = 0; j < 4; ++j) {
        const float4 v = *(const float4*)(src + j * 4);
        T[r][c * 16 + j * 4 + 0] = v.x;
        T[r][c * 16 + j * 4 + 1] = v.y;
        T[r][c * 16 + j * 4 + 2] = v.z;
        T[r][c * 16 + j * 4 + 3] = v.w;
      }
    }
    __syncthreads();
    {
      const int tt = tid & 63;
      const int c2 = tid >> 6;
      short h[16], l[16];
#pragma unroll
      for (int j = 0; j < 16; ++j) {
        const float f = T[c2 * 16 + j][tt];
        h[j] = f2h(f); l[j] = f2h(f - h2f(h[j]));
      }
      const size_t base = ((size_t)b * HW + hw0 + tt) * DIN + din0 + c2 * 16;
      *(f16x8*)(xT_hi + base)     = *(f16x8*)&h[0];
      *(f16x8*)(xT_hi + base + 8) = *(f16x8*)&h[8];
      *(f16x8*)(xT_lo + base)     = *(f16x8*)&l[0];
      *(f16x8*)(xT_lo + base + 8) = *(f16x8*)&l[8];
    }
  }
}

// ---------------- K1: proj_in MFMA: z = xT @ (16 Win)^T / 16 + b_in ----------
__global__ __launch_bounds__(256, 2) void k_proj_in_mfma(
    const short* __restrict__ xT_hi, const short* __restrict__ xT_lo,
    const short* __restrict__ wi_hi, const short* __restrict__ wi_lo,
    const float* __restrict__ bin,
    short* __restrict__ z_hi, short* __restrict__ z_lo) {
  __shared__ short lds_s[4 * 128 * 32];
  char* ldsc = (char*)lds_s;
  const int tid = threadIdx.x;
  const int w = tid >> 6, lane = tid & 63;
  const int quad = lane >> 4, l16 = lane & 15;
  const int wm = w >> 1, wn = w & 1;
  const int tok0 = blockIdx.x * 128;
  const int cd0 = blockIdx.y * 128;

  const int uA = (w << 6) + lane, uB = uA + 256;
  const int tA = uA >> 2, pA = uA & 3, qA = pA ^ ((tA >> 1) & 3);
  const int tB = uB >> 2, pB = uB & 3, qB = pB ^ ((tB >> 1) & 3);
  const int offA = tA * DIN + qA * 8;
  const int offB = tB * DIN + qB * 8;
  const short* gAh0 = xT_hi + (size_t)tok0 * DIN + offA;
  const short* gAh1 = xT_hi + (size_t)tok0 * DIN + offB;
  const short* gAl0 = xT_lo + (size_t)tok0 * DIN + offA;
  const short* gAl1 = xT_lo + (size_t)tok0 * DIN + offB;
  const short* gBh0 = wi_hi + (size_t)cd0 * DIN + offA;
  const short* gBh1 = wi_hi + (size_t)cd0 * DIN + offB;
  const short* gBl0 = wi_lo + (size_t)cd0 * DIN + offA;
  const short* gBl1 = wi_lo + (size_t)cd0 * DIN + offB;

  int aoffs[4], boffs[4];
#pragma unroll
  for (int mi = 0; mi < 4; ++mi) {
    const int t = wm * 64 + mi * 16 + l16;
    aoffs[mi] = t * 64 + (quad ^ ((t >> 1) & 3)) * 16;
  }
#pragma unroll
  for (int ni = 0; ni < 4; ++ni) {
    const int t = wn * 64 + ni * 16 + l16;
    boffs[ni] = 16384 + t * 64 + (quad ^ ((t >> 1) & 3)) * 16;
  }

  f32x4 acc[4][4];
#pragma unroll
  for (int mi = 0; mi < 4; ++mi)
#pragma unroll
    for (int ni = 0; ni < 4; ++ni) acc[mi][ni] = (f32x4){0.f, 0.f, 0.f, 0.f};

  for (int kb = 0; kb < DIN; kb += 32) {
    __syncthreads();
    GLL16(gAh0 + kb, ldsc + ((0 * 4 + w) << 10));
    GLL16(gAh1 + kb, ldsc + ((1 * 4 + w) << 10));
    GLL16(gAl0 + kb, ldsc + ((2 * 4 + w) << 10));
    GLL16(gAl1 + kb, ldsc + ((3 * 4 + w) << 10));
    GLL16(gBh0 + kb, ldsc + ((4 * 4 + w) << 10));
    GLL16(gBh1 + kb, ldsc + ((5 * 4 + w) << 10));
    GLL16(gBl0 + kb, ldsc + ((6 * 4 + w) << 10));
    GLL16(gBl1 + kb, ldsc + ((7 * 4 + w) << 10));
    __syncthreads();
    f16x8 ah[4], al[4], bh[4], bl[4];
#pragma unroll
    for (int mi = 0; mi < 4; ++mi) {
      ah[mi] = *(const f16x8*)(ldsc + aoffs[mi]);
      al[mi] = *(const f16x8*)(ldsc + 8192 + aoffs[mi]);
    }
#pragma unroll
    for (int ni = 0; ni < 4; ++ni) {
      bh[ni] = *(const f16x8*)(ldsc + boffs[ni]);
      bl[ni] = *(const f16x8*)(ldsc + 8192 + boffs[ni]);
    }
#pragma unroll
    for (int mi = 0; mi < 4; ++mi)
#pragma unroll
      for (int ni = 0; ni < 4; ++ni) {
        f32x4 c = acc[mi][ni];
        c = __builtin_amdgcn_mfma_f32_16x16x32_f16(ah[mi], bh[ni], c, 0, 0, 0);
        c = __builtin_amdgcn_mfma_f32_16x16x32_f16(ah[mi], bl[ni], c, 0, 0, 0);
        c = __builtin_amdgcn_mfma_f32_16x16x32_f16(al[mi], bh[ni], c, 0, 0, 0);
        acc[mi][ni] = c;
      }
  }
  float bv[4];
#pragma unroll
  for (int ni = 0; ni < 4; ++ni) bv[ni] = bin[cd0 + wn * 64 + ni * 16 + l16];
#pragma unroll
  for (int mi = 0; mi < 4; ++mi)
#pragma unroll
    for (int r = 0; r < 4; ++r) {
      const int t = tok0 + wm * 64 + mi * 16 + quad * 4 + r;
#pragma unroll
      for (int ni = 0; ni < 4; ++ni) {
        const int cd = cd0 + wn * 64 + ni * 16 + l16;
        const float o = acc[mi][ni][r] * INV_WS + bv[ni];
        const short h = f2h(o);
        z_hi[(size_t)t * CDIM + cd] = h;
        z_lo[(size_t)t * CDIM + cd] = f2h(o - h2f(h));
      }
    }
}

// ---------------- K2: MFMA distance GEMM + per-partial top-2(+idx)/top-3(val) -
// 2 fp16 passes: z_hi * (e_hi + e_lo). Error = 2*z_lo.e, |err| <=
// 2*||z_lo||*||e|| — handled downstream by the 32-candidate exact re-rank.
__global__ __launch_bounds__(256, 2) void k_argmin_mfma(
    const short* __restrict__ z_hi,
    const short* __restrict__ cb_hi, const short* __restrict__ cb_lo,
    const float* __restrict__ ee,
    float* __restrict__ pm1v, int* __restrict__ pm1i,
    float* __restrict__ pm2v, int* __restrict__ pm2i,
    float* __restrict__ pm3v) {
  __shared__ short lds_s[3 * 128 * 32];
  char* ldsc = (char*)lds_s;
  const int tid = threadIdx.x;
  const int w = tid >> 6, lane = tid & 63;
  const int quad = lane >> 4, l16 = lane & 15;
  const int wm = w >> 1, wn = w & 1;
  const int tok0 = blockIdx.x * 128;
  const int cbase = blockIdx.y * CPS;

  const int uA = (w << 6) + lane, uB = uA + 256;
  const int tA = uA >> 2, pA = uA & 3, qA = pA ^ ((tA >> 1) & 3);
  const int tB = uB >> 2, pB = uB & 3, qB = pB ^ ((tB >> 1) & 3);
  const int offA = tA * CDIM + qA * 8;
  const int offB = tB * CDIM + qB * 8;
  const short* gAh0 = z_hi + (size_t)tok0 * CDIM + offA;
  const short* gAh1 = z_hi + (size_t)tok0 * CDIM + offB;

  int aoffs[4], boffs[4];
#pragma unroll
  for (int mi = 0; mi < 4; ++mi) {
    const int t = wm * 64 + mi * 16 + l16;
    aoffs[mi] = t * 64 + (quad ^ ((t >> 1) & 3)) * 16;
  }
#pragma unroll
  for (int ni = 0; ni < 4; ++ni) {
    const int t = wn * 64 + ni * 16 + l16;
    boffs[ni] = 8192 + t * 64 + (quad ^ ((t >> 1) & 3)) * 16;
  }

  float m1v[16], m2v[16], m3v[16]; int m1i[16], m2i[16];
#pragma unroll
  for (int j = 0; j < 16; ++j) {
    m1v[j] = FLT_MAX; m2v[j] = FLT_MAX; m3v[j] = FLT_MAX;
    m1i[j] = 0x7fffffff; m2i[j] = 0x7fffffff;
  }

  for (int ct = 0; ct < CPS / 128; ++ct) {
    const int ctile = cbase + ct * 128;
    const short* gBh0 = cb_hi + (size_t)ctile * CDIM + offA;
    const short* gBh1 = cb_hi + (size_t)ctile * CDIM + offB;
    const short* gBl0 = cb_lo + (size_t)ctile * CDIM + offA;
    const short* gBl1 = cb_lo + (size_t)ctile * CDIM + offB;
    f32x4 acc[4][4];
#pragma unroll
    for (int mi = 0; mi < 4; ++mi)
#pragma unroll
      for (int ni = 0; ni < 4; ++ni) acc[mi][ni] = (f32x4){0.f, 0.f, 0.f, 0.f};

    for (int kb = 0; kb < CDIM; kb += 32) {
      __syncthreads();
      GLL16(gAh0 + kb, ldsc + ((0 * 4 + w) << 10));
      GLL16(gAh1 + kb, ldsc + ((1 * 4 + w) << 10));
      GLL16(gBh0 + kb, ldsc + ((2 * 4 + w) << 10));
      GLL16(gBh1 + kb, ldsc + ((3 * 4 + w) << 10));
      GLL16(gBl0 + kb, ldsc + ((4 * 4 + w) << 10));
      GLL16(gBl1 + kb, ldsc + ((5 * 4 + w) << 10));
      __syncthreads();
      f16x8 ah[4], bh[4], bl[4];
#pragma unroll
      for (int mi = 0; mi < 4; ++mi)
        ah[mi] = *(const f16x8*)(ldsc + aoffs[mi]);
#pragma unroll
      for (int ni = 0; ni < 4; ++ni) {
        bh[ni] = *(const f16x8*)(ldsc + boffs[ni]);
        bl[ni] = *(const f16x8*)(ldsc + 8192 + boffs[ni]);
      }
#pragma unroll
      for (int mi = 0; mi < 4; ++mi)
#pragma unroll
        for (int ni = 0; ni < 4; ++ni) {
          f32x4 c = acc[mi][ni];
          c = __builtin_amdgcn_mfma_f32_16x16x32_f16(ah[mi], bh[ni], c, 0, 0, 0);
          c = __builtin_amdgcn_mfma_f32_16x16x32_f16(ah[mi], bl[ni], c, 0, 0, 0);
          acc[mi][ni] = c;
        }
    }
    float eev[4];
#pragma unroll
    for (int ni = 0; ni < 4; ++ni) eev[ni] = ee[ctile + wn * 64 + ni * 16 + l16];
    const int cb2 = ctile + wn * 64 + l16;
#pragma unroll
    for (int mi = 0; mi < 4; ++mi)
#pragma unroll
      for (int r = 0; r < 4; ++r) {
        const int j = mi * 4 + r;
#pragma unroll
        for (int ni = 0; ni < 4; ++ni) {
          const float s = fmaf(NEG2_INV_WS, acc[mi][ni][r], eev[ni]);
          const int cand = cb2 + ni * 16;
          // sorted top-3 insert (m3 value-only, m1/m2 with index)
          const float o2 = m2v[j];
          m3v[j] = fminf(m3v[j], fmaxf(o2, s));
          const bool b1 = s < m1v[j];
          const bool b2 = s < o2;
          m2v[j] = b1 ? m1v[j] : (b2 ? s : o2);
          m2i[j] = b1 ? m1i[j] : (b2 ? cand : m2i[j]);
          m1v[j] = b1 ? s : m1v[j];
          m1i[j] = b1 ? cand : m1i[j];
        }
      }
  }
  // butterfly merge of 3-tuples across the 16 l16 lanes
#pragma unroll
  for (int off = 1; off < 16; off <<= 1) {
#pragma unroll
    for (int j = 0; j < 16; ++j) {
      const float ov1 = __shfl_xor(m1v[j], off, 64);
      const int   oi1 = __shfl_xor(m1i[j], off, 64);
      const float ov2 = __shfl_xor(m2v[j], off, 64);
      const int   oi2 = __shfl_xor(m2i[j], off, 64);
      const float ov3 = __shfl_xor(m3v[j], off, 64);
      const float m3n = fminf(fminf(m3v[j], ov3),
                              fminf(fmaxf(m1v[j], ov2), fmaxf(m2v[j], ov1)));
      const bool sw = (ov1 < m1v[j]) || (ov1 == m1v[j] && oi1 < m1i[j]);
      const float xv = sw ? m1v[j] : m2v[j];
      const int   xi = sw ? m1i[j] : m2i[j];
      const float yv = sw ? ov2 : ov1;
      const int   yi = sw ? oi2 : oi1;
      const bool s2 = (yv < xv) || (yv == xv && yi < xi);
      m2v[j] = s2 ? yv : xv; m2i[j] = s2 ? yi : xi;
      m1v[j] = sw ? ov1 : m1v[j]; m1i[j] = sw ? oi1 : m1i[j];
      m3v[j] = m3n;
    }
  }
  if (l16 == 0) {
    const int strip = blockIdx.y * 2 + wn;
#pragma unroll
    for (int j = 0; j < 16; ++j) {
      const int mi = j >> 2, r = j & 3;
      const int t = tok0 + wm * 64 + mi * 16 + quad * 4 + r;
      const size_t o = (size_t)strip * NTOK + t;
      pm1v[o] = m1v[j]; pm1i[o] = m1i[j];
      pm2v[o] = m2v[j]; pm2i[o] = m2i[j];
      pm3v[o] = m3v[j];
    }
  }
}

// ---------------- K2b: merge partials + exact 32-candidate re-rank + loss ----
// One wave per token. Completeness: if merged m3 > m1 + band, the true argmin
// is in the per-partial top-2 set (proof: rank>=3 in its partial would force
// partial_m3 <= a(k*) <= m1v + 2B <= flag threshold). Else -> full-scan list.
__global__ __launch_bounds__(256) void k_merge_rescue(
    const float* __restrict__ pm1v, const int* __restrict__ pm1i,
    const float* __restrict__ pm2v, const int* __restrict__ pm2i,
    const float* __restrict__ pm3v,
    const short* __restrict__ z_hi, const short* __restrict__ z_lo,
    const float* __restrict__ cb,
    int* __restrict__ idxi, float* __restrict__ idx_f,
    int* __restrict__ rlist, int* __restrict__ rcount,
    float* __restrict__ loss) {
  __shared__ float lpart[4];
  const int tid = threadIdx.x;
  const int wv = tid >> 6, lane = tid & 63;
  const int t = blockIdx.x * 4 + wv;
  float a1v = FLT_MAX, a2v = FLT_MAX, a3v = FLT_MAX;
  int a1i = 0x7fffffff, a2i = 0x7fffffff;
  if (lane < NPART) {
    const size_t o = (size_t)lane * NTOK + t;
    a1v = pm1v[o]; a1i = pm1i[o];
    a2v = pm2v[o]; a2i = pm2i[o];
    a3v = pm3v[o];
  }
  const int c1i = a1i, c2i = a2i;   // pristine per-partial top-2 (candidates)
#pragma unroll
  for (int off = 1; off < 16; off <<= 1) {
    const float ov1 = __shfl_xor(a1v, off, 64);
    const int   oi1 = __shfl_xor(a1i, off, 64);
    const float ov2 = __shfl_xor(a2v, off, 64);
    const int   oi2 = __shfl_xor(a2i, off, 64);
    const float ov3 = __shfl_xor(a3v, off, 64);
    const float m3n = fminf(fminf(a3v, ov3),
                            fminf(fmaxf(a1v, ov2), fmaxf(a2v, ov1)));
    const bool sw = (ov1 < a1v) || (ov1 == a1v && oi1 < a1i);
    const float xv = sw ? a1v : a2v;
    const int   xi = sw ? a1i : a2i;
    const float yv = sw ? ov2 : ov1;
    const int   yi = sw ? oi2 : oi1;
    const bool s2 = (yv < xv) || (yv == xv && yi < xi);
    a2v = s2 ? yv : xv; a2i = s2 ? yi : xi;
    a1v = sw ? ov1 : a1v; a1i = sw ? oi1 : a1i;
    a3v = m3n;
  }
  const float gm1v = __shfl(a1v, 0, 64);
  const float gm3v = __shfl(a3v, 0, 64);
  // z for this token: 4 dims per lane
  const short4 h4 = *(const short4*)(z_hi + (size_t)t * CDIM + lane * 4);
  const short4 l4 = *(const short4*)(z_lo + (size_t)t * CDIM + lane * 4);
  const float lx = h2f(l4.x), ly = h2f(l4.y), lz = h2f(l4.z), lw = h2f(l4.w);
  const float zx = h2f(h4.x) + lx;
  const float zy = h2f(h4.y) + ly;
  const float zz = h2f(h4.z) + lz;
  const float zw = h2f(h4.w) + lw;
  float zl2 = lx * lx + ly * ly + lz * lz + lw * lw;
#pragma unroll
  for (int off = 32; off > 0; off >>= 1) zl2 += __shfl_xor(zl2, off, 64);
  const float band = 4.0f * sqrtf(zl2) * EMAX_BOUND + 2e-4f;
  // exact fp64 re-rank of the 32 candidates
  double bestv = 1e300; int besti = 0x7fffffff;
#pragma unroll 2
  for (int c = 0; c < 32; ++c) {
    const int ci = (c < 16) ? __shfl(c1i, c, 64) : __shfl(c2i, c - 16, 64);
    const float4 ev = *(const float4*)(cb + (size_t)ci * CDIM + lane * 4);
    const double dx = (double)zx - (double)ev.x;
    const double dy = (double)zy - (double)ev.y;
    const double dz_ = (double)zz - (double)ev.z;
    const double dw = (double)zw - (double)ev.w;
    double d = dx * dx + dy * dy + dz_ * dz_ + dw * dw;
#pragma unroll
    for (int off = 32; off > 0; off >>= 1) d += __shfl_xor(d, off, 64);
    if (d < bestv || (d == bestv && ci < besti)) { bestv = d; besti = ci; }
  }
  // loss with the exact winner (fp32, matches previous rounds)
  const float4 qv = *(const float4*)(cb + (size_t)besti * CDIM + lane * 4);
  const float dx = qv.x - zx;
  const float dy = qv.y - zy;
  const float dz_ = qv.z - zz;
  const float dw = qv.w - zw;
  float s = dx * dx + dy * dy + dz_ * dz_ + dw * dw;
#pragma unroll
  for (int off = 32; off > 0; off >>= 1) s += __shfl_down(s, off, 64);
  if (lane == 0) {
    idxi[t] = besti;
    idx_f[t] = (float)besti;
    lpart[wv] = s;
    if (gm3v - gm1v <= band) {            // candidate set may be incomplete
      const int pos = atomicAdd(rcount, 1);
      if (pos < MAXR) rlist[pos] = t;
    }
  }
  __syncthreads();
  if (tid == 0) {
    atomicAdd(loss, (lpart[0] + lpart[1] + lpart[2] + lpart[3]) * LOSS_SCALE);
  }
}

// ---------------- K2c: chunked fp64 full rescore (rare fallback) --------------
__global__ __launch_bounds__(256) void k_rescue_chunk(
    const short* __restrict__ z_hi, const short* __restrict__ z_lo,
    const float* __restrict__ cb,
    const int* __restrict__ rlist, const int* __restrict__ rcount,
    double* __restrict__ slotv, int* __restrict__ sloti) {
  const int cnt0 = *rcount;
  const int cnt = cnt0 < MAXR ? cnt0 : MAXR;
  const int li0 = blockIdx.x >> 5;
  const int chunk = blockIdx.x & (RCHUNK - 1);
  if (li0 >= cnt) return;
  __shared__ float zrow[CDIM];
  __shared__ double rv[256];
  __shared__ int ri[256];
  const int tid = threadIdx.x;
  for (int li = li0; li < cnt; li += RBLOCKS / RCHUNK) {
    const int t = rlist[li];
    zrow[tid] = h2f(z_hi[(size_t)t * CDIM + tid]) + h2f(z_lo[(size_t)t * CDIM + tid]);
    __syncthreads();
    const int k = chunk * 256 + tid;
    const float* e = cb + (size_t)k * CDIM;
    double s0 = 0.0, s1 = 0.0, s2 = 0.0, s3 = 0.0;
    for (int c = 0; c < CDIM; c += 4) {
      const float4 ev = *(const float4*)(e + c);
      const double d0 = (double)zrow[c]     - (double)ev.x;
      const double d1 = (double)zrow[c + 1] - (double)ev.y;
      const double d2 = (double)zrow[c + 2] - (double)ev.z;
      const double d3 = (double)zrow[c + 3] - (double)ev.w;
      s0 += d0 * d0; s1 += d1 * d1; s2 += d2 * d2; s3 += d3 * d3;
    }
    rv[tid] = (s0 + s1) + (s2 + s3);
    ri[tid] = k;
    __syncthreads();
    for (int off = 128; off > 0; off >>= 1) {
      if (tid < off) {
        if (rv[tid + off] < rv[tid] ||
            (rv[tid + off] == rv[tid] && ri[tid + off] < ri[tid])) {
          rv[tid] = rv[tid + off]; ri[tid] = ri[tid + off];
        }
      }
      __syncthreads();
    }
    if (tid == 0) {
      slotv[(size_t)li * RCHUNK + chunk] = rv[0];
      sloti[(size_t)li * RCHUNK + chunk] = ri[0];
    }
    __syncthreads();
  }
}

// ---------------- K2d: fold chunk slots, patch indices + loss delta -----------
__global__ __launch_bounds__(256) void k_rescue_fin(
    const double* __restrict__ slotv, const int* __restrict__ sloti,
    const int* __restrict__ rlist, const int* __restrict__ rcount,
    const short* __restrict__ z_hi, const short* __restrict__ z_lo,
    const float* __restrict__ cb,
    int* __restrict__ idxi, float* __restrict__ idx_f, float* __restrict__ loss) {
  const int cnt0 = *rcount;
  const int cnt = cnt0 < MAXR ? cnt0 : MAXR;
  const int tid = threadIdx.x;
  const int wv = tid >> 6, lane = tid & 63;
  for (int li = wv; li < cnt; li += 4) {
    double bv = 1e300; int bx = 0x7fffffff;
    if (lane < RCHUNK) {
      bv = slotv[(size_t)li * RCHUNK + lane];
      bx = sloti[(size_t)li * RCHUNK + lane];
    }
#pragma unroll
    for (int off = 1; off < 32; off <<= 1) {
      const double ov = __shfl_xor(bv, off, 64);
      const int   oi = __shfl_xor(bx, off, 64);
      if (ov < bv || (ov == bv && oi < bx)) { bv = ov; bx = oi; }
    }
    const int newi = __shfl(bx, 0, 64);
    const int t = rlist[li];
    const int oldi = idxi[t];
    if (newi != oldi) {
      const short4 h4 = *(const short4*)(z_hi + (size_t)t * CDIM + lane * 4);
      const short4 l4 = *(const short4*)(z_lo + (size_t)t * CDIM + lane * 4);
      const float4 qn = *(const float4*)(cb + (size_t)newi * CDIM + lane * 4);
      const float4 qo = *(const float4*)(cb + (size_t)oldi * CDIM + lane * 4);
      const float zx = h2f(h4.x) + h2f(l4.x);
      const float zy = h2f(h4.y) + h2f(l4.y);
      const float zz = h2f(h4.z) + h2f(l4.z);
      const float zw = h2f(h4.w) + h2f(l4.w);
      float d = (qn.x - zx) * (qn.x - zx) - (qo.x - zx) * (qo.x - zx)
              + (qn.y - zy) * (qn.y - zy) - (qo.y - zy) * (qo.y - zy)
              + (qn.z - zz) * (qn.z - zz) - (qo.z - zz) * (qo.z - zz)
              + (qn.w - zw) * (qn.w - zw) - (qo.w - zw) * (qo.w - zw);
#pragma unroll
      for (int off = 32; off > 0; off >>= 1) d += __shfl_down(d, off, 64);
      if (lane == 0) {
        idxi[t] = newi;
        idx_f[t] = (float)newi;
        atomicAdd(loss, d * LOSS_SCALE);
      }
    }
  }
}

// ---------------- K3: proj_out MFMA (transposed): out[din][tok] ---------------
__global__ __launch_bounds__(256, 2) void k_proj_out_mfma(
    const short* __restrict__ wo_hi,
    const short* __restrict__ cb_hi, const short* __restrict__ cb_lo,
    const int* __restrict__ idxi, const float* __restrict__ bout,
    float* __restrict__ out) {
  __shared__ short lds_s[3 * 128 * 32];
  char* ldsc = (char*)lds_s;
  const int tid = threadIdx.x;
  const int w = tid >> 6, lane = tid & 63;
  const int quad = lane >> 4, l16 = lane & 15;
  const int wm = w >> 1, wn = w & 1;
  const int tok0 = blockIdx.x * 128;
  const int din0 = blockIdx.y * 128;

  const int uA = (w << 6) + lane, uB = uA + 256;
  const int tA = uA >> 2, pA = uA & 3, qA = pA ^ ((tA >> 1) & 3);
  const int tB = uB >> 2, pB = uB & 3, qB = pB ^ ((tB >> 1) & 3);
  const short* gAh0 = wo_hi + (size_t)(din0 + tA) * CDIM + qA * 8;
  const short* gAh1 = wo_hi + (size_t)(din0 + tB) * CDIM + qB * 8;
  const int iA = idxi[tok0 + tA];
  const int iB = idxi[tok0 + tB];
  const short* gBh0 = cb_hi + (size_t)iA * CDIM + qA * 8;
  const short* gBh1 = cb_hi + (size_t)iB * CDIM + qB * 8;
  const short* gBl0 = cb_lo + (size_t)iA * CDIM + qA * 8;
  const short* gBl1 = cb_lo + (size_t)iB * CDIM + qB * 8;

  int aoffs[4], boffs[4];
#pragma unroll
  for (int mi = 0; mi < 4; ++mi) {
    const int t = wm * 64 + mi * 16 + l16;
    aoffs[mi] = t * 64 + (quad ^ ((t >> 1) & 3)) * 16;
  }
#pragma unroll
  for (int ni = 0; ni < 4; ++ni) {
    const int t = wn * 64 + ni * 16 + l16;
    boffs[ni] = 8192 + t * 64 + (quad ^ ((t >> 1) & 3)) * 16;
  }

  f32x4 acc[4][4];
#pragma unroll
  for (int mi = 0; mi < 4; ++mi)
#pragma unroll
    for (int ni = 0; ni < 4; ++ni) acc[mi][ni] = (f32x4){0.f, 0.f, 0.f, 0.f};

  for (int kb = 0; kb < CDIM; kb += 32) {
    __syncthreads();
    GLL16(gAh0 + kb, ldsc + ((0 * 4 + w) << 10));
    GLL16(gAh1 + kb, ldsc + ((1 * 4 + w) << 10));
    GLL16(gBh0 + kb, ldsc + ((2 * 4 + w) << 10));
    GLL16(gBh1 + kb, ldsc + ((3 * 4 + w) << 10));
    GLL16(gBl0 + kb, ldsc + ((4 * 4 + w) << 10));
    GLL16(gBl1 + kb, ldsc + ((5 * 4 + w) << 10));
    __syncthreads();
    f16x8 ah[4], bh[4], bl[4];
#pragma unroll
    for (int mi = 0; mi < 4; ++mi)
      ah[mi] = *(const f16x8*)(ldsc + aoffs[mi]);
#pragma unroll
    for (int ni = 0; ni < 4; ++ni) {
      bh[ni] = *(const f16x8*)(ldsc + boffs[ni]);
      bl[ni] = *(const f16x8*)(ldsc + 8192 + boffs[ni]);
    }
#pragma unroll
    for (int mi = 0; mi < 4; ++mi)
#pragma unroll
      for (int ni = 0; ni < 4; ++ni) {
        f32x4 c = acc[mi][ni];
        c = __builtin_amdgcn_mfma_f32_16x16x32_f16(ah[mi], bh[ni], c, 0, 0, 0);
        c = __builtin_amdgcn_mfma_f32_16x16x32_f16(ah[mi], bl[ni], c, 0, 0, 0);
        acc[mi][ni] = c;
      }
  }
  const int b = tok0 >> 10;
  const int hwb = tok0 & (HW - 1);
  float* ob = out + (size_t)b * DIN * HW;
#pragma unroll
  for (int mi = 0; mi < 4; ++mi)
#pragma unroll
    for (int r = 0; r < 4; ++r) {
      const int din = din0 + wm * 64 + mi * 16 + quad * 4 + r;
      const float bb = bout[din];
#pragma unroll
      for (int ni = 0; ni < 4; ++ni) {
        const int hw = hwb + wn * 64 + ni * 16 + l16;
        ob[(size_t)din * HW + hw] = acc[mi][ni][r] * INV_WS2 + bb;
      }
    }
}

extern "C" void kernel_launch(void* const* d_in, const int* in_sizes, int n_in,
                              void* d_out, int out_size, void* d_ws, size_t ws_size,
                              hipStream_t stream) {
  const float* x    = (const float*)d_in[0];
  const float* Win  = (const float*)d_in[1];
  const float* bin  = (const float*)d_in[2];
  const float* Wout = (const float*)d_in[3];
  const float* bout = (const float*)d_in[4];
  const float* cb   = (const float*)d_in[5];

  float* out   = (float*)d_out;
  float* idx_f = out + OUT_ELEMS;
  float* loss  = out + OUT_ELEMS + NTOK;

  char* w = (char*)d_ws;
  size_t off = 0;
  short* z_hi  = (short*)(w + off); off += (size_t)NTOK * CDIM * 2;
  short* z_lo  = (short*)(w + off); off += (size_t)NTOK * CDIM * 2;
  short* cb_hi = (short*)(w + off); off += (size_t)KCODES * CDIM * 2;
  short* cb_lo = (short*)(w + off); off += (size_t)KCODES * CDIM * 2;
  short* xT_hi = (short*)(w + off); off += (size_t)NTOK * DIN * 2;
  short* xT_lo = (short*)(w + off); off += (size_t)NTOK * DIN * 2;
  short* wi_hi = (short*)(w + off); off += (size_t)CDIM * DIN * 2;
  short* wi_lo = (short*)(w + off); off += (size_t)CDIM * DIN * 2;
  short* wo_hi = (short*)(w + off); off += (size_t)DIN * CDIM * 2;
  short* wo_lo = (short*)(w + off); off += (size_t)DIN * CDIM * 2;
  float* ee    = (float*)(w + off); off += (size_t)KCODES * 4;
  int*   idxi  = (int*)(w + off);   off += (size_t)NTOK * 4;
  float* pm1v  = (float*)(w + off); off += (size_t)NPART * NTOK * 4;
  int*   pm1i  = (int*)(w + off);   off += (size_t)NPART * NTOK * 4;
  float* pm2v  = (float*)(w + off); off += (size_t)NPART * NTOK * 4;
  int*   pm2i  = (int*)(w + off);   off += (size_t)NPART * NTOK * 4;
  float* pm3v  = (float*)(w + off); off += (size_t)NPART * NTOK * 4;
  int*   rlist = (int*)(w + off);   off += (size_t)MAXR * 4;
  int*   rcount= (int*)(w + off);   off += 256;
  double* slotv= (double*)(w + off);off += (size_t)MAXR * RCHUNK * 8;
  int*   sloti = (int*)(w + off);   off += (size_t)MAXR * RCHUNK * 4;

  k_prep        <<<dim3(PREP_CB_BLKS + PREP_W_BLKS + PREP_X_BLKS),
                   dim3(256), 0, stream>>>(cb, Win, Wout, x, cb_hi, cb_lo, ee,
                                           wi_hi, wi_lo, wo_hi, wo_lo,
                                           xT_hi, xT_lo, loss, rcount);
  k_proj_in_mfma<<<dim3(NTOK / 128, CDIM / 128), dim3(256), 0, stream>>>(
      xT_hi, xT_lo, wi_hi, wi_lo, bin, z_hi, z_lo);
  k_argmin_mfma <<<dim3(NTOK / 128, NSTRIP), dim3(256), 0, stream>>>(
      z_hi, cb_hi, cb_lo, ee, pm1v, pm1i, pm2v, pm2i, pm3v);
  k_merge_rescue<<<dim3(NTOK / 4), dim3(256), 0, stream>>>(
      pm1v, pm1i, pm2v, pm2i, pm3v, z_hi, z_lo, cb, idxi, idx_f,
      rlist, rcount, loss);
  k_rescue_chunk<<<dim3(RBLOCKS), dim3(256), 0, stream>>>(
      z_hi, z_lo, cb, rlist, rcount, slotv, sloti);
  k_rescue_fin  <<<dim3(1), dim3(256), 0, stream>>>(
      slotv, sloti, rlist, rcount, z_hi, z_lo, cb, idxi, idx_f, loss);
  k_proj_out_mfma<<<dim3(NTOK / 128, DIN / 128), dim3(256), 0, stream>>>(
      wo_hi, cb_hi, cb_lo, idxi, bout, out);
}

// Round 3
// 399.580 us; speedup vs baseline: 1.4795x; 1.1943x over previous
//
#include <hip/hip_runtime.h>
#include <cfloat>
#include <cstdint>

// VQ-VAE vector quantizer forward. Round 9: 1-pass fp16 argmin.
// argmin GEMM = z_hi x e_hi ONLY (half the MFMA of round 8); rigor restored by
// exact error bound band = 4(||z_lo||*Emax + ||z_hi||*Rmax) + slack, with
// Emax=max||e||, Rmax=max||e - e_hi/16|| computed exactly in prep (atomicMax).
// Partials: 64 per token (strip x wn x l16-group), 5-op top-1+2nd tracking
// (was 10-op top-3), 2-step butterfly. Merge: coalesced [t][64] gather,
// candidate filter (mv <= m1+band); common path (1 candidate, no flag) does
// ZERO fp64; rare multi-candidate -> fp64 re-rank; hidden-rank-2
// (min_p sv <= m1+band, ~quadratic probability) -> full-scan fallback.
#define B_      16
#define DIN     512
#define HW      1024
#define CDIM    256
#define KCODES  8192
#define NTOK    (B_ * HW)            // 16384
#define OUT_ELEMS (B_ * DIN * HW)    // 8388608
#define NSTRIP  8
#define NPART2  64                   // partials per token
#define CPS     (KCODES / NSTRIP)    // 1024
#define MAXR    4096
#define RCHUNK  32
#define RBLOCKS 2048
#define LOSS_SCALE (1.0f / ((float)NTOK * (float)CDIM))
// tensor pre-scale for fp16 splits of small-magnitude tensors
#define WSCALE      16.0f
#define INV_WS      0.0625f          // 1/16  (proj_in:  x * (16 W))
#define INV_WS2     0.00390625f      // 1/256 (proj_out: (16 Wo)*(16 e))
#define NEG2_INV_WS (-0.125f)        // -2/16 (argmin:   z * (16 e))
#define BAND_SLACK  2e-3f            // covers fp32 accum + ee rounding

typedef __attribute__((ext_vector_type(8))) _Float16 f16x8;
typedef __attribute__((ext_vector_type(4))) float f32x4;

static __device__ __forceinline__ short f2h(float f) {
  _Float16 h = (_Float16)f;                  // RNE
  return __builtin_bit_cast(short, h);
}
static __device__ __forceinline__ float h2f(short h) {
  return (float)__builtin_bit_cast(_Float16, h);
}

#define GLL16(gsrc, ldst)                                                      \
  __builtin_amdgcn_global_load_lds(                                           \
      (const __attribute__((address_space(1))) unsigned int*)(gsrc),          \
      (__attribute__((address_space(3))) unsigned int*)(ldst), 16, 0, 0)

// ---------------- K0: fused prep: cb hi/lo + ee + norms | W hi/lo | xT hi/lo -
#define PREP_CB_BLKS 2048
#define PREP_W_BLKS  128
#define PREP_X_BLKS  2048
__global__ __launch_bounds__(256) void k_prep(
    const float* __restrict__ cb, const float* __restrict__ Win,
    const float* __restrict__ Wout, const float* __restrict__ x,
    short* __restrict__ cb_hi, short* __restrict__ cb_lo, float* __restrict__ ee,
    short* __restrict__ wi_hi, short* __restrict__ wi_lo,
    short* __restrict__ wo_hi,
    short* __restrict__ xT_hi, short* __restrict__ xT_lo,
    float* __restrict__ loss, int* __restrict__ rcount, int* __restrict__ scal) {
  __shared__ float T[64][65];
  const int blk = blockIdx.x;
  const int tid = threadIdx.x;
  if (blk == 0 && tid < 2) {
    if (tid == 0) *loss = 0.0f; else *rcount = 0;
  }
  if (blk < PREP_CB_BLKS) {
    const int wid = (blk * 256 + tid) >> 6;
    const int lane = tid & 63;
    const float4 v = *(const float4*)(cb + (size_t)wid * CDIM + lane * 4);
    float s = v.x * v.x + v.y * v.y + v.z * v.z + v.w * v.w;
    const float sx = v.x * WSCALE, sy = v.y * WSCALE,
                sz = v.z * WSCALE, sw = v.w * WSCALE;
    short4 h, l;
    h.x = f2h(sx); l.x = f2h(sx - h2f(h.x));
    h.y = f2h(sy); l.y = f2h(sy - h2f(h.y));
    h.z = f2h(sz); l.z = f2h(sz - h2f(h.z));
    h.w = f2h(sw); l.w = f2h(sw - h2f(h.w));
    *(short4*)(cb_hi + (size_t)wid * CDIM + lane * 4) = h;
    *(short4*)(cb_lo + (size_t)wid * CDIM + lane * 4) = l;
    // residual of the 1-pass argmin approximation: r = e - e_hi/16
    const float rx = v.x - h2f(h.x) * INV_WS;
    const float ry = v.y - h2f(h.y) * INV_WS;
    const float rz = v.z - h2f(h.z) * INV_WS;
    const float rw = v.w - h2f(h.w) * INV_WS;
    float rr = rx * rx + ry * ry + rz * rz + rw * rw;
#pragma unroll
    for (int off = 32; off > 0; off >>= 1) {
      s += __shfl_down(s, off, 64);
      rr += __shfl_down(rr, off, 64);
    }
    const int wv = tid >> 6;
    if (lane == 0) { ee[wid] = s; T[0][wv] = s; T[1][wv] = rr; }
    __syncthreads();
    if (tid == 0) {
      const float em = fmaxf(fmaxf(T[0][0], T[0][1]), fmaxf(T[0][2], T[0][3]));
      const float rm = fmaxf(fmaxf(T[1][0], T[1][1]), fmaxf(T[1][2], T[1][3]));
      atomicMax(scal + 0, __float_as_int(em));   // positive floats: int order
      atomicMax(scal + 1, __float_as_int(rm));
    }
  } else if (blk < PREP_CB_BLKS + PREP_W_BLKS) {
    const int i = ((blk - PREP_CB_BLKS) * 256 + tid) * 4;
    {
      const float4 v = *(const float4*)(Win + i);
      const float sx = v.x * WSCALE, sy = v.y * WSCALE,
                  sz = v.z * WSCALE, sw = v.w * WSCALE;
      short4 h, l;
      h.x = f2h(sx); l.x = f2h(sx - h2f(h.x));
      h.y = f2h(sy); l.y = f2h(sy - h2f(h.y));
      h.z = f2h(sz); l.z = f2h(sz - h2f(h.z));
      h.w = f2h(sw); l.w = f2h(sw - h2f(h.w));
      *(short4*)(wi_hi + i) = h; *(short4*)(wi_lo + i) = l;
    }
    {
      const float4 v = *(const float4*)(Wout + i);
      short4 h;
      h.x = f2h(v.x * WSCALE);
      h.y = f2h(v.y * WSCALE);
      h.z = f2h(v.z * WSCALE);
      h.w = f2h(v.w * WSCALE);
      *(short4*)(wo_hi + i) = h;
    }
  } else {
    const int id = blk - PREP_CB_BLKS - PREP_W_BLKS;
    const int xb = id & 255, yb = id >> 8;
    const int b = xb >> 4;
    const int hw0 = (xb & 15) * 64;
    const int din0 = yb * 64;
    {
      const int r = tid >> 2;
      const int c = tid & 3;
      const float* src = x + ((size_t)b * DIN + din0 + r) * HW + hw0 + c * 16;
#pragma unroll
      for (int j = 0; j < 4; ++j) {
        const float4 v = *(const float4*)(src + j * 4);
        T[r][c * 16 + j * 4 + 0] = v.x;
        T[r][c * 16 + j * 4 + 1] = v.y;
        T[r][c * 16 + j * 4 + 2] = v.z;
        T[r][c * 16 + j * 4 + 3] = v.w;
      }
    }
    __syncthreads();
    {
      const int tt = tid & 63;
      const int c2 = tid >> 6;
      short h[16], l[16];
#pragma unroll
      for (int j = 0; j < 16; ++j) {
        const float f = T[c2 * 16 + j][tt];
        h[j] = f2h(f); l[j] = f2h(f - h2f(h[j]));
      }
      const size_t base = ((size_t)b * HW + hw0 + tt) * DIN + din0 + c2 * 16;
      *(f16x8*)(xT_hi + base)     = *(f16x8*)&h[0];
      *(f16x8*)(xT_hi + base + 8) = *(f16x8*)&h[8];
      *(f16x8*)(xT_lo + base)     = *(f16x8*)&l[0];
      *(f16x8*)(xT_lo + base + 8) = *(f16x8*)&l[8];
    }
  }
}

// ---------------- K1: proj_in MFMA: z = xT @ (16 Win)^T / 16 + b_in ----------
__global__ __launch_bounds__(256, 2) void k_proj_in_mfma(
    const short* __restrict__ xT_hi, const short* __restrict__ xT_lo,
    const short* __restrict__ wi_hi, const short* __restrict__ wi_lo,
    const float* __restrict__ bin,
    short* __restrict__ z_hi, short* __restrict__ z_lo) {
  __shared__ short lds_s[4 * 128 * 32];
  char* ldsc = (char*)lds_s;
  const int tid = threadIdx.x;
  const int w = tid >> 6, lane = tid & 63;
  const int quad = lane >> 4, l16 = lane & 15;
  const int wm = w >> 1, wn = w & 1;
  const int tok0 = blockIdx.x * 128;
  const int cd0 = blockIdx.y * 128;

  const int uA = (w << 6) + lane, uB = uA + 256;
  const int tA = uA >> 2, pA = uA & 3, qA = pA ^ ((tA >> 1) & 3);
  const int tB = uB >> 2, pB = uB & 3, qB = pB ^ ((tB >> 1) & 3);
  const int offA = tA * DIN + qA * 8;
  const int offB = tB * DIN + qB * 8;
  const short* gAh0 = xT_hi + (size_t)tok0 * DIN + offA;
  const short* gAh1 = xT_hi + (size_t)tok0 * DIN + offB;
  const short* gAl0 = xT_lo + (size_t)tok0 * DIN + offA;
  const short* gAl1 = xT_lo + (size_t)tok0 * DIN + offB;
  const short* gBh0 = wi_hi + (size_t)cd0 * DIN + offA;
  const short* gBh1 = wi_hi + (size_t)cd0 * DIN + offB;
  const short* gBl0 = wi_lo + (size_t)cd0 * DIN + offA;
  const short* gBl1 = wi_lo + (size_t)cd0 * DIN + offB;

  int aoffs[4], boffs[4];
#pragma unroll
  for (int mi = 0; mi < 4; ++mi) {
    const int t = wm * 64 + mi * 16 + l16;
    aoffs[mi] = t * 64 + (quad ^ ((t >> 1) & 3)) * 16;
  }
#pragma unroll
  for (int ni = 0; ni < 4; ++ni) {
    const int t = wn * 64 + ni * 16 + l16;
    boffs[ni] = 16384 + t * 64 + (quad ^ ((t >> 1) & 3)) * 16;
  }

  f32x4 acc[4][4];
#pragma unroll
  for (int mi = 0; mi < 4; ++mi)
#pragma unroll
    for (int ni = 0; ni < 4; ++ni) acc[mi][ni] = (f32x4){0.f, 0.f, 0.f, 0.f};

  for (int kb = 0; kb < DIN; kb += 32) {
    __syncthreads();
    GLL16(gAh0 + kb, ldsc + ((0 * 4 + w) << 10));
    GLL16(gAh1 + kb, ldsc + ((1 * 4 + w) << 10));
    GLL16(gAl0 + kb, ldsc + ((2 * 4 + w) << 10));
    GLL16(gAl1 + kb, ldsc + ((3 * 4 + w) << 10));
    GLL16(gBh0 + kb, ldsc + ((4 * 4 + w) << 10));
    GLL16(gBh1 + kb, ldsc + ((5 * 4 + w) << 10));
    GLL16(gBl0 + kb, ldsc + ((6 * 4 + w) << 10));
    GLL16(gBl1 + kb, ldsc + ((7 * 4 + w) << 10));
    __syncthreads();
    f16x8 ah[4], al[4], bh[4], bl[4];
#pragma unroll
    for (int mi = 0; mi < 4; ++mi) {
      ah[mi] = *(const f16x8*)(ldsc + aoffs[mi]);
      al[mi] = *(const f16x8*)(ldsc + 8192 + aoffs[mi]);
    }
#pragma unroll
    for (int ni = 0; ni < 4; ++ni) {
      bh[ni] = *(const f16x8*)(ldsc + boffs[ni]);
      bl[ni] = *(const f16x8*)(ldsc + 8192 + boffs[ni]);
    }
#pragma unroll
    for (int mi = 0; mi < 4; ++mi)
#pragma unroll
      for (int ni = 0; ni < 4; ++ni) {
        f32x4 c = acc[mi][ni];
        c = __builtin_amdgcn_mfma_f32_16x16x32_f16(ah[mi], bh[ni], c, 0, 0, 0);
        c = __builtin_amdgcn_mfma_f32_16x16x32_f16(ah[mi], bl[ni], c, 0, 0, 0);
        c = __builtin_amdgcn_mfma_f32_16x16x32_f16(al[mi], bh[ni], c, 0, 0, 0);
        acc[mi][ni] = c;
      }
  }
  float bv[4];
#pragma unroll
  for (int ni = 0; ni < 4; ++ni) bv[ni] = bin[cd0 + wn * 64 + ni * 16 + l16];
#pragma unroll
  for (int mi = 0; mi < 4; ++mi)
#pragma unroll
    for (int r = 0; r < 4; ++r) {
      const int t = tok0 + wm * 64 + mi * 16 + quad * 4 + r;
#pragma unroll
      for (int ni = 0; ni < 4; ++ni) {
        const int cd = cd0 + wn * 64 + ni * 16 + l16;
        const float o = acc[mi][ni][r] * INV_WS + bv[ni];
        const short h = f2h(o);
        z_hi[(size_t)t * CDIM + cd] = h;
        z_lo[(size_t)t * CDIM + cd] = f2h(o - h2f(h));
      }
    }
}

// ---------------- K2: 1-pass MFMA distance + 64-partial top-1/2nd ------------
// a(k) = ee_k - 0.125 * (z_hi . e_hi). Error vs exact: 2 z_lo.e + 2 z_hi.r,
// bounded downstream via Emax/Rmax. 5-op tracking per candidate.
__global__ __launch_bounds__(256, 2) void k_argmin_mfma(
    const short* __restrict__ z_hi,
    const short* __restrict__ cb_hi,
    const float* __restrict__ ee,
    float* __restrict__ pm1v, int* __restrict__ pm1i, float* __restrict__ pm2v) {
  __shared__ short lds_s[2 * 128 * 32];   // 16 KB: A(z_hi) + B(cb_hi)
  char* ldsc = (char*)lds_s;
  const int tid = threadIdx.x;
  const int w = tid >> 6, lane = tid & 63;
  const int quad = lane >> 4, l16 = lane & 15;
  const int wm = w >> 1, wn = w & 1;
  const int tok0 = blockIdx.x * 128;
  const int cbase = blockIdx.y * CPS;

  const int uA = (w << 6) + lane, uB = uA + 256;
  const int tA = uA >> 2, pA = uA & 3, qA = pA ^ ((tA >> 1) & 3);
  const int tB = uB >> 2, pB = uB & 3, qB = pB ^ ((tB >> 1) & 3);
  const int offA = tA * CDIM + qA * 8;
  const int offB = tB * CDIM + qB * 8;
  const short* gAh0 = z_hi + (size_t)tok0 * CDIM + offA;
  const short* gAh1 = z_hi + (size_t)tok0 * CDIM + offB;

  int aoffs[4], boffs[4];
#pragma unroll
  for (int mi = 0; mi < 4; ++mi) {
    const int t = wm * 64 + mi * 16 + l16;
    aoffs[mi] = t * 64 + (quad ^ ((t >> 1) & 3)) * 16;
  }
#pragma unroll
  for (int ni = 0; ni < 4; ++ni) {
    const int t = wn * 64 + ni * 16 + l16;
    boffs[ni] = 8192 + t * 64 + (quad ^ ((t >> 1) & 3)) * 16;
  }

  float mv[16], sv[16]; int mi_[16];
#pragma unroll
  for (int j = 0; j < 16; ++j) {
    mv[j] = FLT_MAX; sv[j] = FLT_MAX; mi_[j] = 0x7fffffff;
  }

  for (int ct = 0; ct < CPS / 128; ++ct) {
    const int ctile = cbase + ct * 128;
    const short* gBh0 = cb_hi + (size_t)ctile * CDIM + offA;
    const short* gBh1 = cb_hi + (size_t)ctile * CDIM + offB;
    f32x4 acc[4][4];
#pragma unroll
    for (int mi = 0; mi < 4; ++mi)
#pragma unroll
      for (int ni = 0; ni < 4; ++ni) acc[mi][ni] = (f32x4){0.f, 0.f, 0.f, 0.f};

    for (int kb = 0; kb < CDIM; kb += 32) {
      __syncthreads();
      GLL16(gAh0 + kb, ldsc + ((0 * 4 + w) << 10));
      GLL16(gAh1 + kb, ldsc + ((1 * 4 + w) << 10));
      GLL16(gBh0 + kb, ldsc + ((2 * 4 + w) << 10));
      GLL16(gBh1 + kb, ldsc + ((3 * 4 + w) << 10));
      __syncthreads();
      f16x8 ah[4], bh[4];
#pragma unroll
      for (int mi = 0; mi < 4; ++mi)
        ah[mi] = *(const f16x8*)(ldsc + aoffs[mi]);
#pragma unroll
      for (int ni = 0; ni < 4; ++ni)
        bh[ni] = *(const f16x8*)(ldsc + boffs[ni]);
#pragma unroll
      for (int mi = 0; mi < 4; ++mi)
#pragma unroll
        for (int ni = 0; ni < 4; ++ni)
          acc[mi][ni] = __builtin_amdgcn_mfma_f32_16x16x32_f16(
              ah[mi], bh[ni], acc[mi][ni], 0, 0, 0);
    }
    float eev[4];
#pragma unroll
    for (int ni = 0; ni < 4; ++ni) eev[ni] = ee[ctile + wn * 64 + ni * 16 + l16];
    const int cb2 = ctile + wn * 64 + l16;
#pragma unroll
    for (int mi = 0; mi < 4; ++mi)
#pragma unroll
      for (int r = 0; r < 4; ++r) {
        const int j = mi * 4 + r;
#pragma unroll
        for (int ni = 0; ni < 4; ++ni) {
          const float s = fmaf(NEG2_INV_WS, acc[mi][ni][r], eev[ni]);
          sv[j] = fminf(sv[j], fmaxf(mv[j], s));
          if (s < mv[j]) { mv[j] = s; mi_[j] = cb2 + ni * 16; }
        }
      }
  }
  // 2-step butterfly: merge l16 groups of 4 -> 64 partials per token
#pragma unroll
  for (int off = 1; off <= 2; off <<= 1) {
#pragma unroll
    for (int j = 0; j < 16; ++j) {
      const float ov = __shfl_xor(mv[j], off, 64);
      const int   oi = __shfl_xor(mi_[j], off, 64);
      const float os = __shfl_xor(sv[j], off, 64);
      const float snew = fminf(fminf(sv[j], os), fmaxf(mv[j], ov));
      if (ov < mv[j] || (ov == mv[j] && oi < mi_[j])) { mv[j] = ov; mi_[j] = oi; }
      sv[j] = snew;
    }
  }
  if ((l16 & 3) == 0) {
    const int pp = (blockIdx.y * 2 + wn) * 4 + (l16 >> 2);
#pragma unroll
    for (int j = 0; j < 16; ++j) {
      const int mi = j >> 2, r = j & 3;
      const int t = tok0 + wm * 64 + mi * 16 + quad * 4 + r;
      const size_t o = (size_t)t * NPART2 + pp;
      pm1v[o] = mv[j]; pm1i[o] = mi_[j]; pm2v[o] = sv[j];
    }
  }
}

// ---------------- K2b: merge 64 partials + filtered exact re-rank + loss -----
// lane == partial. Common path (1 in-band candidate, no hidden-rank-2 flag):
// winner = m1i, zero fp64. Multi-candidate: fp64 re-rank of ballot survivors.
// Hidden rank-2 possible (min_p sv <= m1+band): full-scan fallback list.
__global__ __launch_bounds__(256) void k_merge_rescue(
    const float* __restrict__ pm1v, const int* __restrict__ pm1i,
    const float* __restrict__ pm2v,
    const short* __restrict__ z_hi, const short* __restrict__ z_lo,
    const float* __restrict__ cb, const int* __restrict__ scal,
    int* __restrict__ idxi, float* __restrict__ idx_f,
    int* __restrict__ rlist, int* __restrict__ rcount,
    float* __restrict__ loss) {
  __shared__ float lpart[4];
  const int tid = threadIdx.x;
  const int wv = tid >> 6, lane = tid & 63;
  const int t = blockIdx.x * 4 + wv;
  const size_t po = (size_t)t * NPART2 + lane;
  const float av = pm1v[po];
  const int   ai = pm1i[po];
  const float asv = pm2v[po];
  // reductions: global (m1v,m1i) and msv = min over partials of 2nd-best
  float m1v = av; int m1i = ai; float msv = asv;
#pragma unroll
  for (int off = 1; off < 64; off <<= 1) {
    const float ov = __shfl_xor(m1v, off, 64);
    const int   oi = __shfl_xor(m1i, off, 64);
    const float os = __shfl_xor(msv, off, 64);
    msv = fminf(msv, os);
    if (ov < m1v || (ov == m1v && oi < m1i)) { m1v = ov; m1i = oi; }
  }
  // z row for this token: 4 dims per lane
  const short4 h4 = *(const short4*)(z_hi + (size_t)t * CDIM + lane * 4);
  const short4 l4 = *(const short4*)(z_lo + (size_t)t * CDIM + lane * 4);
  const float hx = h2f(h4.x), hy = h2f(h4.y), hz = h2f(h4.z), hw = h2f(h4.w);
  const float lx = h2f(l4.x), ly = h2f(l4.y), lz = h2f(l4.z), lw = h2f(l4.w);
  const float zx = hx + lx, zy = hy + ly, zz = hz + lz, zw = hw + lw;
  float zl2 = lx * lx + ly * ly + lz * lz + lw * lw;
  float zh2 = hx * hx + hy * hy + hz * hz + hw * hw;
#pragma unroll
  for (int off = 32; off > 0; off >>= 1) {
    zl2 += __shfl_xor(zl2, off, 64);
    zh2 += __shfl_xor(zh2, off, 64);
  }
  const float emax = sqrtf(__int_as_float(scal[0]));
  const float rmax = sqrtf(__int_as_float(scal[1]));
  const float band = 4.0f * (sqrtf(zl2) * emax + sqrtf(zh2) * rmax) + BAND_SLACK;
  const float thr = m1v + band;
  const unsigned long long ball = __ballot(av <= thr);
  const bool flag = (msv <= thr);
  int besti = m1i;
  if (__popcll(ball) > 1) {
    double bestv = 1e300; int bi = 0x7fffffff;
    unsigned long long bb = ball;
    while (bb) {
      const int c = __ffsll((long long)bb) - 1;
      bb &= bb - 1;
      const int ci = __shfl(ai, c, 64);
      const float4 ev = *(const float4*)(cb + (size_t)ci * CDIM + lane * 4);
      const double dx = (double)zx - (double)ev.x;
      const double dy = (double)zy - (double)ev.y;
      const double dz_ = (double)zz - (double)ev.z;
      const double dw = (double)zw - (double)ev.w;
      double d = dx * dx + dy * dy + dz_ * dz_ + dw * dw;
#pragma unroll
      for (int off = 32; off > 0; off >>= 1) d += __shfl_xor(d, off, 64);
      if (d < bestv || (d == bestv && ci < bi)) { bestv = d; bi = ci; }
    }
    besti = bi;
  }
  // loss with the chosen winner (fp32)
  const float4 qv = *(const float4*)(cb + (size_t)besti * CDIM + lane * 4);
  const float dx = qv.x - zx;
  const float dy = qv.y - zy;
  const float dz_ = qv.z - zz;
  const float dw = qv.w - zw;
  float s = dx * dx + dy * dy + dz_ * dz_ + dw * dw;
#pragma unroll
  for (int off = 32; off > 0; off >>= 1) s += __shfl_down(s, off, 64);
  if (lane == 0) {
    idxi[t] = besti;
    idx_f[t] = (float)besti;
    lpart[wv] = s;
    if (flag) {
      const int pos = atomicAdd(rcount, 1);
      if (pos < MAXR) rlist[pos] = t;
    }
  }
  __syncthreads();
  if (tid == 0) {
    atomicAdd(loss, (lpart[0] + lpart[1] + lpart[2] + lpart[3]) * LOSS_SCALE);
  }
}

// ---------------- K2c: chunked fp64 full rescore (rare fallback) --------------
__global__ __launch_bounds__(256) void k_rescue_chunk(
    const short* __restrict__ z_hi, const short* __restrict__ z_lo,
    const float* __restrict__ cb,
    const int* __restrict__ rlist, const int* __restrict__ rcount,
    double* __restrict__ slotv, int* __restrict__ sloti) {
  const int cnt0 = *rcount;
  const int cnt = cnt0 < MAXR ? cnt0 : MAXR;
  const int li0 = blockIdx.x >> 5;
  const int chunk = blockIdx.x & (RCHUNK - 1);
  if (li0 >= cnt) return;
  __shared__ float zrow[CDIM];
  __shared__ double rv[256];
  __shared__ int ri[256];
  const int tid = threadIdx.x;
  for (int li = li0; li < cnt; li += RBLOCKS / RCHUNK) {
    const int t = rlist[li];
    zrow[tid] = h2f(z_hi[(size_t)t * CDIM + tid]) + h2f(z_lo[(size_t)t * CDIM + tid]);
    __syncthreads();
    const int k = chunk * 256 + tid;
    const float* e = cb + (size_t)k * CDIM;
    double s0 = 0.0, s1 = 0.0, s2 = 0.0, s3 = 0.0;
    for (int c = 0; c < CDIM; c += 4) {
      const float4 ev = *(const float4*)(e + c);
      const double d0 = (double)zrow[c]     - (double)ev.x;
      const double d1 = (double)zrow[c + 1] - (double)ev.y;
      const double d2 = (double)zrow[c + 2] - (double)ev.z;
      const double d3 = (double)zrow[c + 3] - (double)ev.w;
      s0 += d0 * d0; s1 += d1 * d1; s2 += d2 * d2; s3 += d3 * d3;
    }
    rv[tid] = (s0 + s1) + (s2 + s3);
    ri[tid] = k;
    __syncthreads();
    for (int off = 128; off > 0; off >>= 1) {
      if (tid < off) {
        if (rv[tid + off] < rv[tid] ||
            (rv[tid + off] == rv[tid] && ri[tid + off] < ri[tid])) {
          rv[tid] = rv[tid + off]; ri[tid] = ri[tid + off];
        }
      }
      __syncthreads();
    }
    if (tid == 0) {
      slotv[(size_t)li * RCHUNK + chunk] = rv[0];
      sloti[(size_t)li * RCHUNK + chunk] = ri[0];
    }
    __syncthreads();
  }
}

// ---------------- K2d: fold chunk slots, patch indices + loss delta -----------
__global__ __launch_bounds__(256) void k_rescue_fin(
    const double* __restrict__ slotv, const int* __restrict__ sloti,
    const int* __restrict__ rlist, const int* __restrict__ rcount,
    const short* __restrict__ z_hi, const short* __restrict__ z_lo,
    const float* __restrict__ cb,
    int* __restrict__ idxi, float* __restrict__ idx_f, float* __restrict__ loss) {
  const int cnt0 = *rcount;
  const int cnt = cnt0 < MAXR ? cnt0 : MAXR;
  const int tid = threadIdx.x;
  const int wv = tid >> 6, lane = tid & 63;
  for (int li = wv; li < cnt; li += 4) {
    double bv = 1e300; int bx = 0x7fffffff;
    if (lane < RCHUNK) {
      bv = slotv[(size_t)li * RCHUNK + lane];
      bx = sloti[(size_t)li * RCHUNK + lane];
    }
#pragma unroll
    for (int off = 1; off < 32; off <<= 1) {
      const double ov = __shfl_xor(bv, off, 64);
      const int   oi = __shfl_xor(bx, off, 64);
      if (ov < bv || (ov == bv && oi < bx)) { bv = ov; bx = oi; }
    }
    const int newi = __shfl(bx, 0, 64);
    const int t = rlist[li];
    const int oldi = idxi[t];
    if (newi != oldi) {
      const short4 h4 = *(const short4*)(z_hi + (size_t)t * CDIM + lane * 4);
      const short4 l4 = *(const short4*)(z_lo + (size_t)t * CDIM + lane * 4);
      const float4 qn = *(const float4*)(cb + (size_t)newi * CDIM + lane * 4);
      const float4 qo = *(const float4*)(cb + (size_t)oldi * CDIM + lane * 4);
      const float zx = h2f(h4.x) + h2f(l4.x);
      const float zy = h2f(h4.y) + h2f(l4.y);
      const float zz = h2f(h4.z) + h2f(l4.z);
      const float zw = h2f(h4.w) + h2f(l4.w);
      float d = (qn.x - zx) * (qn.x - zx) - (qo.x - zx) * (qo.x - zx)
              + (qn.y - zy) * (qn.y - zy) - (qo.y - zy) * (qo.y - zy)
              + (qn.z - zz) * (qn.z - zz) - (qo.z - zz) * (qo.z - zz)
              + (qn.w - zw) * (qn.w - zw) - (qo.w - zw) * (qo.w - zw);
#pragma unroll
      for (int off = 32; off > 0; off >>= 1) d += __shfl_down(d, off, 64);
      if (lane == 0) {
        idxi[t] = newi;
        idx_f[t] = (float)newi;
        atomicAdd(loss, d * LOSS_SCALE);
      }
    }
  }
}

// ---------------- K3: proj_out MFMA (transposed): out[din][tok] ---------------
__global__ __launch_bounds__(256, 2) void k_proj_out_mfma(
    const short* __restrict__ wo_hi,
    const short* __restrict__ cb_hi, const short* __restrict__ cb_lo,
    const int* __restrict__ idxi, const float* __restrict__ bout,
    float* __restrict__ out) {
  __shared__ short lds_s[3 * 128 * 32];
  char* ldsc = (char*)lds_s;
  const int tid = threadIdx.x;
  const int w = tid >> 6, lane = tid & 63;
  const int quad = lane >> 4, l16 = lane & 15;
  const int wm = w >> 1, wn = w & 1;
  const int tok0 = blockIdx.x * 128;
  const int din0 = blockIdx.y * 128;

  const int uA = (w << 6) + lane, uB = uA + 256;
  const int tA = uA >> 2, pA = uA & 3, qA = pA ^ ((tA >> 1) & 3);
  const int tB = uB >> 2, pB = uB & 3, qB = pB ^ ((tB >> 1) & 3);
  const short* gAh0 = wo_hi + (size_t)(din0 + tA) * CDIM + qA * 8;
  const short* gAh1 = wo_hi + (size_t)(din0 + tB) * CDIM + qB * 8;
  const int iA = idxi[tok0 + tA];
  const int iB = idxi[tok0 + tB];
  const short* gBh0 = cb_hi + (size_t)iA * CDIM + qA * 8;
  const short* gBh1 = cb_hi + (size_t)iB * CDIM + qB * 8;
  const short* gBl0 = cb_lo + (size_t)iA * CDIM + qA * 8;
  const short* gBl1 = cb_lo + (size_t)iB * CDIM + qB * 8;

  int aoffs[4], boffs[4];
#pragma unroll
  for (int mi = 0; mi < 4; ++mi) {
    const int t = wm * 64 + mi * 16 + l16;
    aoffs[mi] = t * 64 + (quad ^ ((t >> 1) & 3)) * 16;
  }
#pragma unroll
  for (int ni = 0; ni < 4; ++ni) {
    const int t = wn * 64 + ni * 16 + l16;
    boffs[ni] = 8192 + t * 64 + (quad ^ ((t >> 1) & 3)) * 16;
  }

  f32x4 acc[4][4];
#pragma unroll
  for (int mi = 0; mi < 4; ++mi)
#pragma unroll
    for (int ni = 0; ni < 4; ++ni) acc[mi][ni] = (f32x4){0.f, 0.f, 0.f, 0.f};

  for (int kb = 0; kb < CDIM; kb += 32) {
    __syncthreads();
    GLL16(gAh0 + kb, ldsc + ((0 * 4 + w) << 10));
    GLL16(gAh1 + kb, ldsc + ((1 * 4 + w) << 10));
    GLL16(gBh0 + kb, ldsc + ((2 * 4 + w) << 10));
    GLL16(gBh1 + kb, ldsc + ((3 * 4 + w) << 10));
    GLL16(gBl0 + kb, ldsc + ((4 * 4 + w) << 10));
    GLL16(gBl1 + kb, ldsc + ((5 * 4 + w) << 10));
    __syncthreads();
    f16x8 ah[4], bh[4], bl[4];
#pragma unroll
    for (int mi = 0; mi < 4; ++mi)
      ah[mi] = *(const f16x8*)(ldsc + aoffs[mi]);
#pragma unroll
    for (int ni = 0; ni < 4; ++ni) {
      bh[ni] = *(const f16x8*)(ldsc + boffs[ni]);
      bl[ni] = *(const f16x8*)(ldsc + 8192 + boffs[ni]);
    }
#pragma unroll
    for (int mi = 0; mi < 4; ++mi)
#pragma unroll
      for (int ni = 0; ni < 4; ++ni) {
        f32x4 c = acc[mi][ni];
        c = __builtin_amdgcn_mfma_f32_16x16x32_f16(ah[mi], bh[ni], c, 0, 0, 0);
        c = __builtin_amdgcn_mfma_f32_16x16x32_f16(ah[mi], bl[ni], c, 0, 0, 0);
        acc[mi][ni] = c;
      }
  }
  const int b = tok0 >> 10;
  const int hwb = tok0 & (HW - 1);
  float* ob = out + (size_t)b * DIN * HW;
#pragma unroll
  for (int mi = 0; mi < 4; ++mi)
#pragma unroll
    for (int r = 0; r < 4; ++r) {
      const int din = din0 + wm * 64 + mi * 16 + quad * 4 + r;
      const float bb = bout[din];
#pragma unroll
      for (int ni = 0; ni < 4; ++ni) {
        const int hw = hwb + wn * 64 + ni * 16 + l16;
        ob[(size_t)din * HW + hw] = acc[mi][ni][r] * INV_WS2 + bb;
      }
    }
}

extern "C" void kernel_launch(void* const* d_in, const int* in_sizes, int n_in,
                              void* d_out, int out_size, void* d_ws, size_t ws_size,
                              hipStream_t stream) {
  const float* x    = (const float*)d_in[0];
  const float* Win  = (const float*)d_in[1];
  const float* bin  = (const float*)d_in[2];
  const float* Wout = (const float*)d_in[3];
  const float* bout = (const float*)d_in[4];
  const float* cb   = (const float*)d_in[5];

  float* out   = (float*)d_out;
  float* idx_f = out + OUT_ELEMS;
  float* loss  = out + OUT_ELEMS + NTOK;

  char* w = (char*)d_ws;
  size_t off = 0;
  short* z_hi  = (short*)(w + off); off += (size_t)NTOK * CDIM * 2;
  short* z_lo  = (short*)(w + off); off += (size_t)NTOK * CDIM * 2;
  short* cb_hi = (short*)(w + off); off += (size_t)KCODES * CDIM * 2;
  short* cb_lo = (short*)(w + off); off += (size_t)KCODES * CDIM * 2;
  short* xT_hi = (short*)(w + off); off += (size_t)NTOK * DIN * 2;
  short* xT_lo = (short*)(w + off); off += (size_t)NTOK * DIN * 2;
  short* wi_hi = (short*)(w + off); off += (size_t)CDIM * DIN * 2;
  short* wi_lo = (short*)(w + off); off += (size_t)CDIM * DIN * 2;
  short* wo_hi = (short*)(w + off); off += (size_t)DIN * CDIM * 2;
  float* ee    = (float*)(w + off); off += (size_t)KCODES * 4;
  int*   idxi  = (int*)(w + off);   off += (size_t)NTOK * 4;
  float* pm1v  = (float*)(w + off); off += (size_t)NPART2 * NTOK * 4;
  int*   pm1i  = (int*)(w + off);   off += (size_t)NPART2 * NTOK * 4;
  float* pm2v  = (float*)(w + off); off += (size_t)NPART2 * NTOK * 4;
  int*   rlist = (int*)(w + off);   off += (size_t)MAXR * 4;
  int*   rcount= (int*)(w + off);   off += 256;
  int*   scal  = (int*)(w + off);   off += 256;
  double* slotv= (double*)(w + off);off += (size_t)MAXR * RCHUNK * 8;
  int*   sloti = (int*)(w + off);   off += (size_t)MAXR * RCHUNK * 4;

  hipMemsetAsync(scal, 0, 8, stream);
  k_prep        <<<dim3(PREP_CB_BLKS + PREP_W_BLKS + PREP_X_BLKS),
                   dim3(256), 0, stream>>>(cb, Win, Wout, x, cb_hi, cb_lo, ee,
                                           wi_hi, wi_lo, wo_hi,
                                           xT_hi, xT_lo, loss, rcount, scal);
  k_proj_in_mfma<<<dim3(NTOK / 128, CDIM / 128), dim3(256), 0, stream>>>(
      xT_hi, xT_lo, wi_hi, wi_lo, bin, z_hi, z_lo);
  k_argmin_mfma <<<dim3(NTOK / 128, NSTRIP), dim3(256), 0, stream>>>(
      z_hi, cb_hi, ee, pm1v, pm1i, pm2v);
  k_merge_rescue<<<dim3(NTOK / 4), dim3(256), 0, stream>>>(
      pm1v, pm1i, pm2v, z_hi, z_lo, cb, scal, idxi, idx_f,
      rlist, rcount, loss);
  k_rescue_chunk<<<dim3(RBLOCKS), dim3(256), 0, stream>>>(
      z_hi, z_lo, cb, rlist, rcount, slotv, sloti);
  k_rescue_fin  <<<dim3(1), dim3(256), 0, stream>>>(
      slotv, sloti, rlist, rcount, z_hi, z_lo, cb, idxi, idx_f, loss);
  k_proj_out_mfma<<<dim3(NTOK / 128, DIN / 128), dim3(256), 0, stream>>>(
      wo_hi, cb_hi, cb_lo, idxi, bout, out);
}

// Round 4
// 387.738 us; speedup vs baseline: 1.5246x; 1.0305x over previous
//
#include <hip/hip_runtime.h>
#include <cfloat>
#include <cstdint>

// VQ-VAE vector quantizer forward. Round 10: argmin loop restructure.
// A (z_hi 128x256 fp16, 64 KB) staged ONCE per block in LDS; B (codebook)
// double-buffered 2x8 KB, ONE barrier per K-step (was 2), prefetch issued
// before MFMA so L2 latency hides under compute. Partials stored as
// [strip][tok][8] (dense 4 KB/block region -> no HBM write amplification;
// was [t][64] = 4B dwords at 256B stride, 70 MB measured for 12.6 MB data).
// Exactness machinery unchanged from round 9 (band + filtered re-rank +
// rare full-scan fallback).
#define B_      16
#define DIN     512
#define HW      1024
#define CDIM    256
#define KCODES  8192
#define NTOK    (B_ * HW)            // 16384
#define OUT_ELEMS (B_ * DIN * HW)    // 8388608
#define NSTRIP  8
#define NPART2  64                   // partials per token
#define CPS     (KCODES / NSTRIP)    // 1024
#define MAXR    4096
#define RCHUNK  32
#define RBLOCKS 2048
#define LOSS_SCALE (1.0f / ((float)NTOK * (float)CDIM))
// tensor pre-scale for fp16 splits of small-magnitude tensors
#define WSCALE      16.0f
#define INV_WS      0.0625f          // 1/16  (proj_in:  x * (16 W))
#define INV_WS2     0.00390625f      // 1/256 (proj_out: (16 Wo)*(16 e))
#define NEG2_INV_WS (-0.125f)        // -2/16 (argmin:   z * (16 e))
#define BAND_SLACK  2e-3f            // covers fp32 accum + ee rounding

typedef __attribute__((ext_vector_type(8))) _Float16 f16x8;
typedef __attribute__((ext_vector_type(4))) float f32x4;

static __device__ __forceinline__ short f2h(float f) {
  _Float16 h = (_Float16)f;                  // RNE
  return __builtin_bit_cast(short, h);
}
static __device__ __forceinline__ float h2f(short h) {
  return (float)__builtin_bit_cast(_Float16, h);
}

#define GLL16(gsrc, ldst)                                                      \
  __builtin_amdgcn_global_load_lds(                                           \
      (const __attribute__((address_space(1))) unsigned int*)(gsrc),          \
      (__attribute__((address_space(3))) unsigned int*)(ldst), 16, 0, 0)

// ---------------- K0: fused prep: cb hi/lo + ee + norms | W hi/lo | xT hi/lo -
#define PREP_CB_BLKS 2048
#define PREP_W_BLKS  128
#define PREP_X_BLKS  2048
__global__ __launch_bounds__(256) void k_prep(
    const float* __restrict__ cb, const float* __restrict__ Win,
    const float* __restrict__ Wout, const float* __restrict__ x,
    short* __restrict__ cb_hi, short* __restrict__ cb_lo, float* __restrict__ ee,
    short* __restrict__ wi_hi, short* __restrict__ wi_lo,
    short* __restrict__ wo_hi,
    short* __restrict__ xT_hi, short* __restrict__ xT_lo,
    float* __restrict__ loss, int* __restrict__ rcount, int* __restrict__ scal) {
  __shared__ float T[64][65];
  const int blk = blockIdx.x;
  const int tid = threadIdx.x;
  if (blk == 0 && tid < 2) {
    if (tid == 0) *loss = 0.0f; else *rcount = 0;
  }
  if (blk < PREP_CB_BLKS) {
    const int wid = (blk * 256 + tid) >> 6;
    const int lane = tid & 63;
    const float4 v = *(const float4*)(cb + (size_t)wid * CDIM + lane * 4);
    float s = v.x * v.x + v.y * v.y + v.z * v.z + v.w * v.w;
    const float sx = v.x * WSCALE, sy = v.y * WSCALE,
                sz = v.z * WSCALE, sw = v.w * WSCALE;
    short4 h, l;
    h.x = f2h(sx); l.x = f2h(sx - h2f(h.x));
    h.y = f2h(sy); l.y = f2h(sy - h2f(h.y));
    h.z = f2h(sz); l.z = f2h(sz - h2f(h.z));
    h.w = f2h(sw); l.w = f2h(sw - h2f(h.w));
    *(short4*)(cb_hi + (size_t)wid * CDIM + lane * 4) = h;
    *(short4*)(cb_lo + (size_t)wid * CDIM + lane * 4) = l;
    // residual of the 1-pass argmin approximation: r = e - e_hi/16
    const float rx = v.x - h2f(h.x) * INV_WS;
    const float ry = v.y - h2f(h.y) * INV_WS;
    const float rz = v.z - h2f(h.z) * INV_WS;
    const float rw = v.w - h2f(h.w) * INV_WS;
    float rr = rx * rx + ry * ry + rz * rz + rw * rw;
#pragma unroll
    for (int off = 32; off > 0; off >>= 1) {
      s += __shfl_down(s, off, 64);
      rr += __shfl_down(rr, off, 64);
    }
    const int wv = tid >> 6;
    if (lane == 0) { ee[wid] = s; T[0][wv] = s; T[1][wv] = rr; }
    __syncthreads();
    if (tid == 0) {
      const float em = fmaxf(fmaxf(T[0][0], T[0][1]), fmaxf(T[0][2], T[0][3]));
      const float rm = fmaxf(fmaxf(T[1][0], T[1][1]), fmaxf(T[1][2], T[1][3]));
      atomicMax(scal + 0, __float_as_int(em));   // positive floats: int order
      atomicMax(scal + 1, __float_as_int(rm));
    }
  } else if (blk < PREP_CB_BLKS + PREP_W_BLKS) {
    const int i = ((blk - PREP_CB_BLKS) * 256 + tid) * 4;
    {
      const float4 v = *(const float4*)(Win + i);
      const float sx = v.x * WSCALE, sy = v.y * WSCALE,
                  sz = v.z * WSCALE, sw = v.w * WSCALE;
      short4 h, l;
      h.x = f2h(sx); l.x = f2h(sx - h2f(h.x));
      h.y = f2h(sy); l.y = f2h(sy - h2f(h.y));
      h.z = f2h(sz); l.z = f2h(sz - h2f(h.z));
      h.w = f2h(sw); l.w = f2h(sw - h2f(h.w));
      *(short4*)(wi_hi + i) = h; *(short4*)(wi_lo + i) = l;
    }
    {
      const float4 v = *(const float4*)(Wout + i);
      short4 h;
      h.x = f2h(v.x * WSCALE);
      h.y = f2h(v.y * WSCALE);
      h.z = f2h(v.z * WSCALE);
      h.w = f2h(v.w * WSCALE);
      *(short4*)(wo_hi + i) = h;
    }
  } else {
    const int id = blk - PREP_CB_BLKS - PREP_W_BLKS;
    const int xb = id & 255, yb = id >> 8;
    const int b = xb >> 4;
    const int hw0 = (xb & 15) * 64;
    const int din0 = yb * 64;
    {
      const int r = tid >> 2;
      const int c = tid & 3;
      const float* src = x + ((size_t)b * DIN + din0 + r) * HW + hw0 + c * 16;
#pragma unroll
      for (int j = 0; j < 4; ++j) {
        const float4 v = *(const float4*)(src + j * 4);
        T[r][c * 16 + j * 4 + 0] = v.x;
        T[r][c * 16 + j * 4 + 1] = v.y;
        T[r][c * 16 + j * 4 + 2] = v.z;
        T[r][c * 16 + j * 4 + 3] = v.w;
      }
    }
    __syncthreads();
    {
      const int tt = tid & 63;
      const int c2 = tid >> 6;
      short h[16], l[16];
#pragma unroll
      for (int j = 0; j < 16; ++j) {
        const float f = T[c2 * 16 + j][tt];
        h[j] = f2h(f); l[j] = f2h(f - h2f(h[j]));
      }
      const size_t base = ((size_t)b * HW + hw0 + tt) * DIN + din0 + c2 * 16;
      *(f16x8*)(xT_hi + base)     = *(f16x8*)&h[0];
      *(f16x8*)(xT_hi + base + 8) = *(f16x8*)&h[8];
      *(f16x8*)(xT_lo + base)     = *(f16x8*)&l[0];
      *(f16x8*)(xT_lo + base + 8) = *(f16x8*)&l[8];
    }
  }
}

// ---------------- K1: proj_in MFMA: z = xT @ (16 Win)^T / 16 + b_in ----------
__global__ __launch_bounds__(256, 2) void k_proj_in_mfma(
    const short* __restrict__ xT_hi, const short* __restrict__ xT_lo,
    const short* __restrict__ wi_hi, const short* __restrict__ wi_lo,
    const float* __restrict__ bin,
    short* __restrict__ z_hi, short* __restrict__ z_lo) {
  __shared__ short lds_s[4 * 128 * 32];
  char* ldsc = (char*)lds_s;
  const int tid = threadIdx.x;
  const int w = tid >> 6, lane = tid & 63;
  const int quad = lane >> 4, l16 = lane & 15;
  const int wm = w >> 1, wn = w & 1;
  const int tok0 = blockIdx.x * 128;
  const int cd0 = blockIdx.y * 128;

  const int uA = (w << 6) + lane, uB = uA + 256;
  const int tA = uA >> 2, pA = uA & 3, qA = pA ^ ((tA >> 1) & 3);
  const int tB = uB >> 2, pB = uB & 3, qB = pB ^ ((tB >> 1) & 3);
  const int offA = tA * DIN + qA * 8;
  const int offB = tB * DIN + qB * 8;
  const short* gAh0 = xT_hi + (size_t)tok0 * DIN + offA;
  const short* gAh1 = xT_hi + (size_t)tok0 * DIN + offB;
  const short* gAl0 = xT_lo + (size_t)tok0 * DIN + offA;
  const short* gAl1 = xT_lo + (size_t)tok0 * DIN + offB;
  const short* gBh0 = wi_hi + (size_t)cd0 * DIN + offA;
  const short* gBh1 = wi_hi + (size_t)cd0 * DIN + offB;
  const short* gBl0 = wi_lo + (size_t)cd0 * DIN + offA;
  const short* gBl1 = wi_lo + (size_t)cd0 * DIN + offB;

  int aoffs[4], boffs[4];
#pragma unroll
  for (int mi = 0; mi < 4; ++mi) {
    const int t = wm * 64 + mi * 16 + l16;
    aoffs[mi] = t * 64 + (quad ^ ((t >> 1) & 3)) * 16;
  }
#pragma unroll
  for (int ni = 0; ni < 4; ++ni) {
    const int t = wn * 64 + ni * 16 + l16;
    boffs[ni] = 16384 + t * 64 + (quad ^ ((t >> 1) & 3)) * 16;
  }

  f32x4 acc[4][4];
#pragma unroll
  for (int mi = 0; mi < 4; ++mi)
#pragma unroll
    for (int ni = 0; ni < 4; ++ni) acc[mi][ni] = (f32x4){0.f, 0.f, 0.f, 0.f};

  for (int kb = 0; kb < DIN; kb += 32) {
    __syncthreads();
    GLL16(gAh0 + kb, ldsc + ((0 * 4 + w) << 10));
    GLL16(gAh1 + kb, ldsc + ((1 * 4 + w) << 10));
    GLL16(gAl0 + kb, ldsc + ((2 * 4 + w) << 10));
    GLL16(gAl1 + kb, ldsc + ((3 * 4 + w) << 10));
    GLL16(gBh0 + kb, ldsc + ((4 * 4 + w) << 10));
    GLL16(gBh1 + kb, ldsc + ((5 * 4 + w) << 10));
    GLL16(gBl0 + kb, ldsc + ((6 * 4 + w) << 10));
    GLL16(gBl1 + kb, ldsc + ((7 * 4 + w) << 10));
    __syncthreads();
    f16x8 ah[4], al[4], bh[4], bl[4];
#pragma unroll
    for (int mi = 0; mi < 4; ++mi) {
      ah[mi] = *(const f16x8*)(ldsc + aoffs[mi]);
      al[mi] = *(const f16x8*)(ldsc + 8192 + aoffs[mi]);
    }
#pragma unroll
    for (int ni = 0; ni < 4; ++ni) {
      bh[ni] = *(const f16x8*)(ldsc + boffs[ni]);
      bl[ni] = *(const f16x8*)(ldsc + 8192 + boffs[ni]);
    }
#pragma unroll
    for (int mi = 0; mi < 4; ++mi)
#pragma unroll
      for (int ni = 0; ni < 4; ++ni) {
        f32x4 c = acc[mi][ni];
        c = __builtin_amdgcn_mfma_f32_16x16x32_f16(ah[mi], bh[ni], c, 0, 0, 0);
        c = __builtin_amdgcn_mfma_f32_16x16x32_f16(ah[mi], bl[ni], c, 0, 0, 0);
        c = __builtin_amdgcn_mfma_f32_16x16x32_f16(al[mi], bh[ni], c, 0, 0, 0);
        acc[mi][ni] = c;
      }
  }
  float bv[4];
#pragma unroll
  for (int ni = 0; ni < 4; ++ni) bv[ni] = bin[cd0 + wn * 64 + ni * 16 + l16];
#pragma unroll
  for (int mi = 0; mi < 4; ++mi)
#pragma unroll
    for (int r = 0; r < 4; ++r) {
      const int t = tok0 + wm * 64 + mi * 16 + quad * 4 + r;
#pragma unroll
      for (int ni = 0; ni < 4; ++ni) {
        const int cd = cd0 + wn * 64 + ni * 16 + l16;
        const float o = acc[mi][ni][r] * INV_WS + bv[ni];
        const short h = f2h(o);
        z_hi[(size_t)t * CDIM + cd] = h;
        z_lo[(size_t)t * CDIM + cd] = f2h(o - h2f(h));
      }
    }
}

// ---------------- K2: 1-pass MFMA distance, A-resident LDS, B dbuf ----------
// A (z_hi tile, 64 KB) staged once; B streamed double-buffered, 1 barrier
// per K-step, prefetch before MFMA. 5-op top-1/2nd tracking, 64 partials.
__global__ __launch_bounds__(256, 2) void k_argmin_mfma(
    const short* __restrict__ z_hi,
    const short* __restrict__ cb_hi,
    const float* __restrict__ ee,
    float* __restrict__ pm1v, int* __restrict__ pm1i, float* __restrict__ pm2v) {
  // 80 KB: A chunks 0..7 at c*8192, B dbuf at 65536 + buf*8192
  __shared__ short lds_s[(8 + 2) * 128 * 32];
  char* ldsc = (char*)lds_s;
  const int tid = threadIdx.x;
  const int w = tid >> 6, lane = tid & 63;
  const int quad = lane >> 4, l16 = lane & 15;
  const int wm = w >> 1, wn = w & 1;
  const int tok0 = blockIdx.x * 128;
  const int cbase = blockIdx.y * CPS;

  const int uA = (w << 6) + lane, uB = uA + 256;
  const int tA = uA >> 2, pA = uA & 3, qA = pA ^ ((tA >> 1) & 3);
  const int tB = uB >> 2, pB = uB & 3, qB = pB ^ ((tB >> 1) & 3);
  const int offA = tA * CDIM + qA * 8;
  const int offB = tB * CDIM + qB * 8;
  const short* gAh0 = z_hi + (size_t)tok0 * CDIM + offA;
  const short* gAh1 = z_hi + (size_t)tok0 * CDIM + offB;
  const short* cbB = cb_hi + (size_t)cbase * CDIM;

  int aoffs[4], boffs[4];
#pragma unroll
  for (int mi = 0; mi < 4; ++mi) {
    const int t = wm * 64 + mi * 16 + l16;
    aoffs[mi] = t * 64 + (quad ^ ((t >> 1) & 3)) * 16;
  }
#pragma unroll
  for (int ni = 0; ni < 4; ++ni) {
    const int t = wn * 64 + ni * 16 + l16;
    boffs[ni] = t * 64 + (quad ^ ((t >> 1) & 3)) * 16;
  }

  float mv[16], sv[16]; int mi_[16];
#pragma unroll
  for (int j = 0; j < 16; ++j) {
    mv[j] = FLT_MAX; sv[j] = FLT_MAX; mi_[j] = 0x7fffffff;
  }

  // prologue: stage all of A (8 chunks) + first B tile chunk into buf 0
#pragma unroll
  for (int c = 0; c < 8; ++c) {
    GLL16(gAh0 + c * 32, ldsc + c * 8192 + (w << 10));
    GLL16(gAh1 + c * 32, ldsc + c * 8192 + 4096 + (w << 10));
  }
  GLL16(cbB + offA, ldsc + 65536 + (w << 10));
  GLL16(cbB + offB, ldsc + 65536 + 4096 + (w << 10));
  __syncthreads();

  int buf = 0;
  for (int ct = 0; ct < 8; ++ct) {
    f32x4 acc[4][4];
#pragma unroll
    for (int mi = 0; mi < 4; ++mi)
#pragma unroll
      for (int ni = 0; ni < 4; ++ni) acc[mi][ni] = (f32x4){0.f, 0.f, 0.f, 0.f};

    for (int kbi = 0; kbi < 8; ++kbi) {
      const int step = ct * 8 + kbi;
      // prefetch next B chunk into the other buffer (before compute)
      if (step + 1 < 64) {
        const int ns = step + 1;
        const size_t nbase = ((size_t)(ns >> 3) << 15) + ((ns & 7) << 5);
        char* bdst = ldsc + 65536 + ((buf ^ 1) << 13);
        GLL16(cbB + nbase + offA, bdst + (w << 10));
        GLL16(cbB + nbase + offB, bdst + 4096 + (w << 10));
      }
      const int abase = kbi << 13;
      const char* bbase = ldsc + 65536 + (buf << 13);
      f16x8 ah[4], bh[4];
#pragma unroll
      for (int mi = 0; mi < 4; ++mi)
        ah[mi] = *(const f16x8*)(ldsc + abase + aoffs[mi]);
#pragma unroll
      for (int ni = 0; ni < 4; ++ni)
        bh[ni] = *(const f16x8*)(bbase + boffs[ni]);
#pragma unroll
      for (int mi = 0; mi < 4; ++mi)
#pragma unroll
        for (int ni = 0; ni < 4; ++ni)
          acc[mi][ni] = __builtin_amdgcn_mfma_f32_16x16x32_f16(
              ah[mi], bh[ni], acc[mi][ni], 0, 0, 0);
      __syncthreads();   // drains prefetch (vmcnt) + orders buffer reuse
      buf ^= 1;
    }
    const int ctile = cbase + ct * 128;
    float eev[4];
#pragma unroll
    for (int ni = 0; ni < 4; ++ni) eev[ni] = ee[ctile + wn * 64 + ni * 16 + l16];
    const int cb2 = ctile + wn * 64 + l16;
#pragma unroll
    for (int mi = 0; mi < 4; ++mi)
#pragma unroll
      for (int r = 0; r < 4; ++r) {
        const int j = mi * 4 + r;
#pragma unroll
        for (int ni = 0; ni < 4; ++ni) {
          const float s = fmaf(NEG2_INV_WS, acc[mi][ni][r], eev[ni]);
          sv[j] = fminf(sv[j], fmaxf(mv[j], s));
          if (s < mv[j]) { mv[j] = s; mi_[j] = cb2 + ni * 16; }
        }
      }
  }
  // 2-step butterfly: merge l16 groups of 4 -> 64 partials per token
#pragma unroll
  for (int off = 1; off <= 2; off <<= 1) {
#pragma unroll
    for (int j = 0; j < 16; ++j) {
      const float ov = __shfl_xor(mv[j], off, 64);
      const int   oi = __shfl_xor(mi_[j], off, 64);
      const float os = __shfl_xor(sv[j], off, 64);
      const float snew = fminf(fminf(sv[j], os), fmaxf(mv[j], ov));
      if (ov < mv[j] || (ov == mv[j] && oi < mi_[j])) { mv[j] = ov; mi_[j] = oi; }
      sv[j] = snew;
    }
  }
  if ((l16 & 3) == 0) {
    const int sub = wn * 4 + (l16 >> 2);
#pragma unroll
    for (int j = 0; j < 16; ++j) {
      const int mi = j >> 2, r = j & 3;
      const int t = tok0 + wm * 64 + mi * 16 + quad * 4 + r;
      // dense layout: [strip][tok][8] -> block footprint is 4 KB contiguous
      const size_t o = ((size_t)blockIdx.y * NTOK + t) * 8 + sub;
      pm1v[o] = mv[j]; pm1i[o] = mi_[j]; pm2v[o] = sv[j];
    }
  }
}

// ---------------- K2b: merge 64 partials + filtered exact re-rank + loss -----
__global__ __launch_bounds__(256) void k_merge_rescue(
    const float* __restrict__ pm1v, const int* __restrict__ pm1i,
    const float* __restrict__ pm2v,
    const short* __restrict__ z_hi, const short* __restrict__ z_lo,
    const float* __restrict__ cb, const int* __restrict__ scal,
    int* __restrict__ idxi, float* __restrict__ idx_f,
    int* __restrict__ rlist, int* __restrict__ rcount,
    float* __restrict__ loss) {
  __shared__ float lpart[4];
  const int tid = threadIdx.x;
  const int wv = tid >> 6, lane = tid & 63;
  const int t = blockIdx.x * 4 + wv;
  // lane = partial: strip = lane>>3, sub = lane&7, layout [strip][tok][8]
  const size_t po = ((size_t)(lane >> 3) * NTOK + t) * 8 + (lane & 7);
  const float av = pm1v[po];
  const int   ai = pm1i[po];
  const float asv = pm2v[po];
  // reductions: global (m1v,m1i) and msv = min over partials of 2nd-best
  float m1v = av; int m1i = ai; float msv = asv;
#pragma unroll
  for (int off = 1; off < 64; off <<= 1) {
    const float ov = __shfl_xor(m1v, off, 64);
    const int   oi = __shfl_xor(m1i, off, 64);
    const float os = __shfl_xor(msv, off, 64);
    msv = fminf(msv, os);
    if (ov < m1v || (ov == m1v && oi < m1i)) { m1v = ov; m1i = oi; }
  }
  // z row for this token: 4 dims per lane
  const short4 h4 = *(const short4*)(z_hi + (size_t)t * CDIM + lane * 4);
  const short4 l4 = *(const short4*)(z_lo + (size_t)t * CDIM + lane * 4);
  const float hx = h2f(h4.x), hy = h2f(h4.y), hz = h2f(h4.z), hw = h2f(h4.w);
  const float lx = h2f(l4.x), ly = h2f(l4.y), lz = h2f(l4.z), lw = h2f(l4.w);
  const float zx = hx + lx, zy = hy + ly, zz = hz + lz, zw = hw + lw;
  float zl2 = lx * lx + ly * ly + lz * lz + lw * lw;
  float zh2 = hx * hx + hy * hy + hz * hz + hw * hw;
#pragma unroll
  for (int off = 32; off > 0; off >>= 1) {
    zl2 += __shfl_xor(zl2, off, 64);
    zh2 += __shfl_xor(zh2, off, 64);
  }
  const float emax = sqrtf(__int_as_float(scal[0]));
  const float rmax = sqrtf(__int_as_float(scal[1]));
  const float band = 4.0f * (sqrtf(zl2) * emax + sqrtf(zh2) * rmax) + BAND_SLACK;
  const float thr = m1v + band;
  const unsigned long long ball = __ballot(av <= thr);
  const bool flag = (msv <= thr);
  int besti = m1i;
  if (__popcll(ball) > 1) {
    double bestv = 1e300; int bi = 0x7fffffff;
    unsigned long long bb = ball;
    while (bb) {
      const int c = __ffsll((long long)bb) - 1;
      bb &= bb - 1;
      const int ci = __shfl(ai, c, 64);
      const float4 ev = *(const float4*)(cb + (size_t)ci * CDIM + lane * 4);
      const double dx = (double)zx - (double)ev.x;
      const double dy = (double)zy - (double)ev.y;
      const double dz_ = (double)zz - (double)ev.z;
      const double dw = (double)zw - (double)ev.w;
      double d = dx * dx + dy * dy + dz_ * dz_ + dw * dw;
#pragma unroll
      for (int off = 32; off > 0; off >>= 1) d += __shfl_xor(d, off, 64);
      if (d < bestv || (d == bestv && ci < bi)) { bestv = d; bi = ci; }
    }
    besti = bi;
  }
  // loss with the chosen winner (fp32)
  const float4 qv = *(const float4*)(cb + (size_t)besti * CDIM + lane * 4);
  const float dx = qv.x - zx;
  const float dy = qv.y - zy;
  const float dz_ = qv.z - zz;
  const float dw = qv.w - zw;
  float s = dx * dx + dy * dy + dz_ * dz_ + dw * dw;
#pragma unroll
  for (int off = 32; off > 0; off >>= 1) s += __shfl_down(s, off, 64);
  if (lane == 0) {
    idxi[t] = besti;
    idx_f[t] = (float)besti;
    lpart[wv] = s;
    if (flag) {
      const int pos = atomicAdd(rcount, 1);
      if (pos < MAXR) rlist[pos] = t;
    }
  }
  __syncthreads();
  if (tid == 0) {
    atomicAdd(loss, (lpart[0] + lpart[1] + lpart[2] + lpart[3]) * LOSS_SCALE);
  }
}

// ---------------- K2c: chunked fp64 full rescore (rare fallback) --------------
__global__ __launch_bounds__(256) void k_rescue_chunk(
    const short* __restrict__ z_hi, const short* __restrict__ z_lo,
    const float* __restrict__ cb,
    const int* __restrict__ rlist, const int* __restrict__ rcount,
    double* __restrict__ slotv, int* __restrict__ sloti) {
  const int cnt0 = *rcount;
  const int cnt = cnt0 < MAXR ? cnt0 : MAXR;
  const int li0 = blockIdx.x >> 5;
  const int chunk = blockIdx.x & (RCHUNK - 1);
  if (li0 >= cnt) return;
  __shared__ float zrow[CDIM];
  __shared__ double rv[256];
  __shared__ int ri[256];
  const int tid = threadIdx.x;
  for (int li = li0; li < cnt; li += RBLOCKS / RCHUNK) {
    const int t = rlist[li];
    zrow[tid] = h2f(z_hi[(size_t)t * CDIM + tid]) + h2f(z_lo[(size_t)t * CDIM + tid]);
    __syncthreads();
    const int k = chunk * 256 + tid;
    const float* e = cb + (size_t)k * CDIM;
    double s0 = 0.0, s1 = 0.0, s2 = 0.0, s3 = 0.0;
    for (int c = 0; c < CDIM; c += 4) {
      const float4 ev = *(const float4*)(e + c);
      const double d0 = (double)zrow[c]     - (double)ev.x;
      const double d1 = (double)zrow[c + 1] - (double)ev.y;
      const double d2 = (double)zrow[c + 2] - (double)ev.z;
      const double d3 = (double)zrow[c + 3] - (double)ev.w;
      s0 += d0 * d0; s1 += d1 * d1; s2 += d2 * d2; s3 += d3 * d3;
    }
    rv[tid] = (s0 + s1) + (s2 + s3);
    ri[tid] = k;
    __syncthreads();
    for (int off = 128; off > 0; off >>= 1) {
      if (tid < off) {
        if (rv[tid + off] < rv[tid] ||
            (rv[tid + off] == rv[tid] && ri[tid + off] < ri[tid])) {
          rv[tid] = rv[tid + off]; ri[tid] = ri[tid + off];
        }
      }
      __syncthreads();
    }
    if (tid == 0) {
      slotv[(size_t)li * RCHUNK + chunk] = rv[0];
      sloti[(size_t)li * RCHUNK + chunk] = ri[0];
    }
    __syncthreads();
  }
}

// ---------------- K2d: fold chunk slots, patch indices + loss delta -----------
__global__ __launch_bounds__(256) void k_rescue_fin(
    const double* __restrict__ slotv, const int* __restrict__ sloti,
    const int* __restrict__ rlist, const int* __restrict__ rcount,
    const short* __restrict__ z_hi, const short* __restrict__ z_lo,
    const float* __restrict__ cb,
    int* __restrict__ idxi, float* __restrict__ idx_f, float* __restrict__ loss) {
  const int cnt0 = *rcount;
  const int cnt = cnt0 < MAXR ? cnt0 : MAXR;
  const int tid = threadIdx.x;
  const int wv = tid >> 6, lane = tid & 63;
  for (int li = wv; li < cnt; li += 4) {
    double bv = 1e300; int bx = 0x7fffffff;
    if (lane < RCHUNK) {
      bv = slotv[(size_t)li * RCHUNK + lane];
      bx = sloti[(size_t)li * RCHUNK + lane];
    }
#pragma unroll
    for (int off = 1; off < 32; off <<= 1) {
      const double ov = __shfl_xor(bv, off, 64);
      const int   oi = __shfl_xor(bx, off, 64);
      if (ov < bv || (ov == bv && oi < bx)) { bv = ov; bx = oi; }
    }
    const int newi = __shfl(bx, 0, 64);
    const int t = rlist[li];
    const int oldi = idxi[t];
    if (newi != oldi) {
      const short4 h4 = *(const short4*)(z_hi + (size_t)t * CDIM + lane * 4);
      const short4 l4 = *(const short4*)(z_lo + (size_t)t * CDIM + lane * 4);
      const float4 qn = *(const float4*)(cb + (size_t)newi * CDIM + lane * 4);
      const float4 qo = *(const float4*)(cb + (size_t)oldi * CDIM + lane * 4);
      const float zx = h2f(h4.x) + h2f(l4.x);
      const float zy = h2f(h4.y) + h2f(l4.y);
      const float zz = h2f(h4.z) + h2f(l4.z);
      const float zw = h2f(h4.w) + h2f(l4.w);
      float d = (qn.x - zx) * (qn.x - zx) - (qo.x - zx) * (qo.x - zx)
              + (qn.y - zy) * (qn.y - zy) - (qo.y - zy) * (qo.y - zy)
              + (qn.z - zz) * (qn.z - zz) - (qo.z - zz) * (qo.z - zz)
              + (qn.w - zw) * (qn.w - zw) - (qo.w - zw) * (qo.w - zw);
#pragma unroll
      for (int off = 32; off > 0; off >>= 1) d += __shfl_down(d, off, 64);
      if (lane == 0) {
        idxi[t] = newi;
        idx_f[t] = (float)newi;
        atomicAdd(loss, d * LOSS_SCALE);
      }
    }
  }
}

// ---------------- K3: proj_out MFMA (transposed): out[din][tok] ---------------
__global__ __launch_bounds__(256, 2) void k_proj_out_mfma(
    const short* __restrict__ wo_hi,
    const short* __restrict__ cb_hi, const short* __restrict__ cb_lo,
    const int* __restrict__ idxi, const float* __restrict__ bout,
    float* __restrict__ out) {
  __shared__ short lds_s[3 * 128 * 32];
  char* ldsc = (char*)lds_s;
  const int tid = threadIdx.x;
  const int w = tid >> 6, lane = tid & 63;
  const int quad = lane >> 4, l16 = lane & 15;
  const int wm = w >> 1, wn = w & 1;
  const int tok0 = blockIdx.x * 128;
  const int din0 = blockIdx.y * 128;

  const int uA = (w << 6) + lane, uB = uA + 256;
  const int tA = uA >> 2, pA = uA & 3, qA = pA ^ ((tA >> 1) & 3);
  const int tB = uB >> 2, pB = uB & 3, qB = pB ^ ((tB >> 1) & 3);
  const short* gAh0 = wo_hi + (size_t)(din0 + tA) * CDIM + qA * 8;
  const short* gAh1 = wo_hi + (size_t)(din0 + tB) * CDIM + qB * 8;
  const int iA = idxi[tok0 + tA];
  const int iB = idxi[tok0 + tB];
  const short* gBh0 = cb_hi + (size_t)iA * CDIM + qA * 8;
  const short* gBh1 = cb_hi + (size_t)iB * CDIM + qB * 8;
  const short* gBl0 = cb_lo + (size_t)iA * CDIM + qA * 8;
  const short* gBl1 = cb_lo + (size_t)iB * CDIM + qB * 8;

  int aoffs[4], boffs[4];
#pragma unroll
  for (int mi = 0; mi < 4; ++mi) {
    const int t = wm * 64 + mi * 16 + l16;
    aoffs[mi] = t * 64 + (quad ^ ((t >> 1) & 3)) * 16;
  }
#pragma unroll
  for (int ni = 0; ni < 4; ++ni) {
    const int t = wn * 64 + ni * 16 + l16;
    boffs[ni] = 8192 + t * 64 + (quad ^ ((t >> 1) & 3)) * 16;
  }

  f32x4 acc[4][4];
#pragma unroll
  for (int mi = 0; mi < 4; ++mi)
#pragma unroll
    for (int ni = 0; ni < 4; ++ni) acc[mi][ni] = (f32x4){0.f, 0.f, 0.f, 0.f};

  for (int kb = 0; kb < CDIM; kb += 32) {
    __syncthreads();
    GLL16(gAh0 + kb, ldsc + ((0 * 4 + w) << 10));
    GLL16(gAh1 + kb, ldsc + ((1 * 4 + w) << 10));
    GLL16(gBh0 + kb, ldsc + ((2 * 4 + w) << 10));
    GLL16(gBh1 + kb, ldsc + ((3 * 4 + w) << 10));
    GLL16(gBl0 + kb, ldsc + ((4 * 4 + w) << 10));
    GLL16(gBl1 + kb, ldsc + ((5 * 4 + w) << 10));
    __syncthreads();
    f16x8 ah[4], bh[4], bl[4];
#pragma unroll
    for (int mi = 0; mi < 4; ++mi)
      ah[mi] = *(const f16x8*)(ldsc + aoffs[mi]);
#pragma unroll
    for (int ni = 0; ni < 4; ++ni) {
      bh[ni] = *(const f16x8*)(ldsc + boffs[ni]);
      bl[ni] = *(const f16x8*)(ldsc + 8192 + boffs[ni]);
    }
#pragma unroll
    for (int mi = 0; mi < 4; ++mi)
#pragma unroll
      for (int ni = 0; ni < 4; ++ni) {
        f32x4 c = acc[mi][ni];
        c = __builtin_amdgcn_mfma_f32_16x16x32_f16(ah[mi], bh[ni], c, 0, 0, 0);
        c = __builtin_amdgcn_mfma_f32_16x16x32_f16(ah[mi], bl[ni], c, 0, 0, 0);
        acc[mi][ni] = c;
      }
  }
  const int b = tok0 >> 10;
  const int hwb = tok0 & (HW - 1);
  float* ob = out + (size_t)b * DIN * HW;
#pragma unroll
  for (int mi = 0; mi < 4; ++mi)
#pragma unroll
    for (int r = 0; r < 4; ++r) {
      const int din = din0 + wm * 64 + mi * 16 + quad * 4 + r;
      const float bb = bout[din];
#pragma unroll
      for (int ni = 0; ni < 4; ++ni) {
        const int hw = hwb + wn * 64 + ni * 16 + l16;
        ob[(size_t)din * HW + hw] = acc[mi][ni][r] * INV_WS2 + bb;
      }
    }
}

extern "C" void kernel_launch(void* const* d_in, const int* in_sizes, int n_in,
                              void* d_out, int out_size, void* d_ws, size_t ws_size,
                              hipStream_t stream) {
  const float* x    = (const float*)d_in[0];
  const float* Win  = (const float*)d_in[1];
  const float* bin  = (const float*)d_in[2];
  const float* Wout = (const float*)d_in[3];
  const float* bout = (const float*)d_in[4];
  const float* cb   = (const float*)d_in[5];

  float* out   = (float*)d_out;
  float* idx_f = out + OUT_ELEMS;
  float* loss  = out + OUT_ELEMS + NTOK;

  char* w = (char*)d_ws;
  size_t off = 0;
  short* z_hi  = (short*)(w + off); off += (size_t)NTOK * CDIM * 2;
  short* z_lo  = (short*)(w + off); off += (size_t)NTOK * CDIM * 2;
  short* cb_hi = (short*)(w + off); off += (size_t)KCODES * CDIM * 2;
  short* cb_lo = (short*)(w + off); off += (size_t)KCODES * CDIM * 2;
  short* xT_hi = (short*)(w + off); off += (size_t)NTOK * DIN * 2;
  short* xT_lo = (short*)(w + off); off += (size_t)NTOK * DIN * 2;
  short* wi_hi = (short*)(w + off); off += (size_t)CDIM * DIN * 2;
  short* wi_lo = (short*)(w + off); off += (size_t)CDIM * DIN * 2;
  short* wo_hi = (short*)(w + off); off += (size_t)DIN * CDIM * 2;
  float* ee    = (float*)(w + off); off += (size_t)KCODES * 4;
  int*   idxi  = (int*)(w + off);   off += (size_t)NTOK * 4;
  float* pm1v  = (float*)(w + off); off += (size_t)NPART2 * NTOK * 4;
  int*   pm1i  = (int*)(w + off);   off += (size_t)NPART2 * NTOK * 4;
  float* pm2v  = (float*)(w + off); off += (size_t)NPART2 * NTOK * 4;
  int*   rlist = (int*)(w + off);   off += (size_t)MAXR * 4;
  int*   rcount= (int*)(w + off);   off += 256;
  int*   scal  = (int*)(w + off);   off += 256;
  double* slotv= (double*)(w + off);off += (size_t)MAXR * RCHUNK * 8;
  int*   sloti = (int*)(w + off);   off += (size_t)MAXR * RCHUNK * 4;

  hipMemsetAsync(scal, 0, 8, stream);
  k_prep        <<<dim3(PREP_CB_BLKS + PREP_W_BLKS + PREP_X_BLKS),
                   dim3(256), 0, stream>>>(cb, Win, Wout, x, cb_hi, cb_lo, ee,
                                           wi_hi, wi_lo, wo_hi,
                                           xT_hi, xT_lo, loss, rcount, scal);
  k_proj_in_mfma<<<dim3(NTOK / 128, CDIM / 128), dim3(256), 0, stream>>>(
      xT_hi, xT_lo, wi_hi, wi_lo, bin, z_hi, z_lo);
  k_argmin_mfma <<<dim3(NTOK / 128, NSTRIP), dim3(256), 0, stream>>>(
      z_hi, cb_hi, ee, pm1v, pm1i, pm2v);
  k_merge_rescue<<<dim3(NTOK / 4), dim3(256), 0, stream>>>(
      pm1v, pm1i, pm2v, z_hi, z_lo, cb, scal, idxi, idx_f,
      rlist, rcount, loss);
  k_rescue_chunk<<<dim3(RBLOCKS), dim3(256), 0, stream>>>(
      z_hi, z_lo, cb, rlist, rcount, slotv, sloti);
  k_rescue_fin  <<<dim3(1), dim3(256), 0, stream>>>(
      slotv, sloti, rlist, rcount, z_hi, z_lo, cb, idxi, idx_f, loss);
  k_proj_out_mfma<<<dim3(NTOK / 128, DIN / 128), dim3(256), 0, stream>>>(
      wo_hi, cb_hi, cb_lo, idxi, bout, out);
}